// Round 10
// baseline (268.192 us; speedup 1.0000x reference)
//
#include <hip/hip_runtime.h>
#include <hip/hip_bf16.h>

#define SEQ    512
#define DMODEL 512
#define NHEAD  8
#define DK     64
#define BS     16
#define NBH    (BS*NHEAD)       // 128
#define HSZ    (SEQ*DK)         // 32768 per (b,h)
#define L2E    1.4426950408889634f

typedef __attribute__((ext_vector_type(8))) short bf16x8;
typedef __attribute__((ext_vector_type(4))) float f32x4;

#define MFMA32(A,B,C) __builtin_amdgcn_mfma_f32_16x16x32_bf16(A,B,C,0,0,0)

// ---------------- workspace layout (fp32 units) ----------------
#define WS_GAM 16ull
#define WS_AQM 256ull
#define WS_AQC (WS_AQM +  65536ull)
#define WS_BKM (WS_AQM + 131072ull)
#define WS_BKC (WS_AQM + 196608ull)
#define WS_AQF (WS_AQM + 262144ull)
#define WS_BKF (WS_AQM + 327680ull)
#define WS_OM  1048576ull
#define WS_OC  (WS_OM + 4194304ull)
#define WS_BF  (WS_OC + 4194304ull)     // bf16 arrays region
#define ARRE   4194304ull               // elems per bf16 array
// bf16 array ids
#define A_QMH 0
#define A_QML 1
#define A_SCH 2
#define A_SCL 3
#define A_KMH 4
#define A_SKH 6
#define A_VMT 8
#define A_VCT 9

__device__ __forceinline__ unsigned short* warr(float* wsf, int idx) {
  return (unsigned short*)(wsf + WS_BF) + (size_t)idx * ARRE;
}

// ---------- helpers ----------
__device__ __forceinline__ float bf2f(unsigned short h) {
  union { float f; unsigned u; } v; v.u = ((unsigned)h) << 16; return v.f;
}
__device__ __forceinline__ unsigned short f2bf(float f) {
  union { float f; unsigned u; } v; v.f = f;
  unsigned u = v.u;
  u += 0x7FFFu + ((u >> 16) & 1u);   // RNE
  return (unsigned short)(u >> 16);
}
__device__ __forceinline__ void ld8_f32(const float* p, float* v) {
  float4 a = *(const float4*)p; float4 b = *(const float4*)(p+4);
  v[0]=a.x;v[1]=a.y;v[2]=a.z;v[3]=a.w;v[4]=b.x;v[5]=b.y;v[6]=b.z;v[7]=b.w;
}
// pack 2 fp32 -> [bf16(a) | bf16(b)<<16], round-half-up, via v_perm
__device__ __forceinline__ unsigned pk2bf(float a, float b) {
  union { float f; unsigned u; } x, y;
  x.f = a; y.f = b;
  return __builtin_amdgcn_perm(y.u + 0x8000u, x.u + 0x8000u, 0x07060302u);
}
__device__ __forceinline__ uint4 cvt8r(const float* t8) {
  uint4 h;
  h.x = pk2bf(t8[0], t8[1]);
  h.y = pk2bf(t8[2], t8[3]);
  h.z = pk2bf(t8[4], t8[5]);
  h.w = pk2bf(t8[6], t8[7]);
  return h;
}
__device__ __forceinline__ uint4 cvt8h(const float* p) {
  float t8[8]; ld8_f32(p, t8); return cvt8r(t8);
}

__global__ void k_gamma(const float* __restrict__ g_in, float* __restrict__ wsf) {
  int t = threadIdx.x;
  if (t >= NHEAD) return;
  float g = g_in[t];
  float sp = (g > 20.f) ? g : log1pf(expf(g));
  (wsf + WS_GAM)[t] = -sp * L2E;     // log2 domain
}

// ---------------- projections: 1-term bf16 MFMA (consistent rounding) ----------------
// y: 0 qm, 1 km, 2 qc, 3 kc, 4 vm, 5 vc
__global__ __launch_bounds__(256) void k_projM(
    const float* xqm, const float* xqc, const float* xkm, const float* xkc,
    const float* xvm, const float* xvc,
    const float* wqm, const float* wqc, const float* wkm, const float* wkc,
    const float* wvm, const float* wvc,
    float* wsf)
{
  __shared__ __align__(16) unsigned short Ah[4096];
  __shared__ __align__(16) unsigned short Bh[4096];
  const int y = blockIdx.y;
  const float* X; const float* W;
  unsigned short *outh = nullptr, *outl = nullptr;
  float* sums = nullptr;
  float qscale = 1.0f; int mode = 0;  // 0 mean, 1 cov, 2 v
  switch (y) {
    case 0: X=xqm; W=wqm; outh=warr(wsf,A_QMH); outl=warr(wsf,A_QML); sums=wsf+WS_AQM; qscale=0.25f*L2E; mode=0; break;
    case 1: X=xkm; W=wkm; outh=warr(wsf,A_KMH); outl=nullptr;         sums=wsf+WS_BKM; qscale=1.0f;      mode=0; break;
    case 2: X=xqc; W=wqc; outh=warr(wsf,A_SCH); outl=warr(wsf,A_SCL); sums=wsf+WS_AQC; qscale=0.25f*L2E; mode=1; break;
    case 3: X=xkc; W=wkc; outh=warr(wsf,A_SKH); outl=nullptr;         sums=wsf+WS_BKC; qscale=1.0f;      mode=1; break;
    case 4: X=xvm; W=wvm; outh=warr(wsf,A_VMT); mode=2; break;
    default:X=xvc; W=wvc; outh=warr(wsf,A_VCT); mode=2; break;
  }
  const int tid = threadIdx.x;
  const int l = tid & 63, li = l & 15, lg = l >> 4;
  const int w = tid >> 6, wr = w >> 1, wc = w & 1;
  const int blk = blockIdx.x;
  const int xcd = blk & 7, qq = blk >> 3;           // qq 0..31
  const int m0 = (xcd*8 + (qq & 7)) * 128;
  const int n0 = (qq >> 3) * 128;
  const int r0 = tid >> 2, c0 = tid & 3, r1 = r0 + 64;
  const int wo0 = r0*64 + ((c0 ^ ((r0>>1)&3))*16);
  const int wo1 = r1*64 + ((c0 ^ ((r1>>1)&3))*16);
  int roA[4], roB[4];
#pragma unroll
  for (int mi = 0; mi < 4; ++mi) {
    int r  = wr*64 + mi*16 + li;
    roA[mi] = r*64 + ((lg ^ ((r>>1)&3))*16);
    int rn = wc*64 + mi*16 + li;
    roB[mi] = rn*64 + ((lg ^ ((rn>>1)&3))*16);
  }
  const float* xp0 = X + (size_t)(m0+r0)*DMODEL + c0*8;
  const float* xp1 = X + (size_t)(m0+r1)*DMODEL + c0*8;
  const float* wp0 = W + (size_t)(n0+r0)*DMODEL + c0*8;
  const float* wp1 = W + (size_t)(n0+r1)*DMODEL + c0*8;
  uint4 a0 = cvt8h(xp0);
  uint4 a1 = cvt8h(xp1);
  uint4 b0 = cvt8h(wp0);
  uint4 b1 = cvt8h(wp1);

  f32x4 acc[4][4];
  f32x4 z = {0.f,0.f,0.f,0.f};
#pragma unroll
  for (int a = 0; a < 4; ++a)
#pragma unroll
    for (int b = 0; b < 4; ++b) acc[a][b] = z;

  for (int kt = 0; kt < DMODEL; kt += 32) {
    __syncthreads();
    *(uint4*)((char*)Ah + wo0) = a0;
    *(uint4*)((char*)Ah + wo1) = a1;
    *(uint4*)((char*)Bh + wo0) = b0;
    *(uint4*)((char*)Bh + wo1) = b1;
    __syncthreads();
    if (kt + 32 < DMODEL) {
      a0 = cvt8h(xp0 + kt + 32);
      a1 = cvt8h(xp1 + kt + 32);
      b0 = cvt8h(wp0 + kt + 32);
      b1 = cvt8h(wp1 + kt + 32);
    }
    bf16x8 ah[4], bh[4];
#pragma unroll
    for (int mi = 0; mi < 4; ++mi) {
      ah[mi] = *(const bf16x8*)((const char*)Ah + roA[mi]);
      bh[mi] = *(const bf16x8*)((const char*)Bh + roB[mi]);
    }
#pragma unroll
    for (int mi = 0; mi < 4; ++mi)
#pragma unroll
      for (int nj = 0; nj < 4; ++nj)
        acc[mi][nj] = MFMA32(ah[mi], bh[nj], acc[mi][nj]);
  }

  const int head = ((n0 >> 6) + wc);
  if (mode <= 1) {
    const bool kside = (outl == nullptr);
#pragma unroll
    for (int mi = 0; mi < 4; ++mi)
#pragma unroll
      for (int reg = 0; reg < 4; ++reg) {
        float rs = 0.f;
#pragma unroll
        for (int nj = 0; nj < 4; ++nj) {
          float v = acc[mi][nj][reg];
          if (mode == 0) {
            float vs = (kside) ? bf2f(f2bf(v)) : v;   // consistent with stored K
            rs += vs*vs;
          } else {
            rs += v;                                   // raw cov sum (reference semantics)
          }
        }
        rs += __shfl_xor(rs, 1); rs += __shfl_xor(rs, 2);
        rs += __shfl_xor(rs, 4); rs += __shfl_xor(rs, 8);
        if (li == 0) {
          int m = m0 + wr*64 + mi*16 + 4*lg + reg;
          sums[((size_t)(m >> 9)*NHEAD + head)*SEQ + (m & 511)] = rs;
        }
      }
#pragma unroll
    for (int mi = 0; mi < 4; ++mi)
#pragma unroll
      for (int nj = 0; nj < 4; ++nj)
#pragma unroll
        for (int reg = 0; reg < 4; ++reg) {
          float v = acc[mi][nj][reg];
          if (mode == 1) v = sqrtf(fmaxf(v, 1e-24f));
          v *= qscale;
          unsigned short h16 = f2bf(v);
          int m = m0 + wr*64 + mi*16 + 4*lg + reg;
          int n = n0 + wc*64 + nj*16 + li;
          size_t dst = ((size_t)((m >> 9)*NHEAD + (n >> 6))*SEQ + (m & 511))*DK + (n & 63);
          outh[dst] = h16;
          if (outl) outl[dst] = f2bf(v - bf2f(h16));
        }
  } else {
    // V: transposed [bh][d][s], 4 consecutive s per store
#pragma unroll
    for (int mi = 0; mi < 4; ++mi)
#pragma unroll
      for (int nj = 0; nj < 4; ++nj) {
        int mb = m0 + wr*64 + mi*16 + 4*lg;
        int n = n0 + wc*64 + nj*16 + li;
        int b = mb >> 9, s = mb & 511, d = n & 63;
        unsigned e0 = f2bf(acc[mi][nj][0]);
        unsigned e1 = f2bf(acc[mi][nj][1]);
        unsigned e2 = f2bf(acc[mi][nj][2]);
        unsigned e3 = f2bf(acc[mi][nj][3]);
        uint2 pk; pk.x = e0 | (e1 << 16); pk.y = e2 | (e3 << 16);
        *(uint2*)(outh + ((size_t)(b*NHEAD + head)*DK + d)*SEQ + s) = pk;
      }
  }
}

__global__ void k_sumAB(float* wsf) {
  int i = blockIdx.x * 256 + threadIdx.x;
  if (i < NBH*SEQ) {
    (wsf+WS_AQF)[i] = (0.125f*L2E) * ((wsf+WS_AQM)[i] + (wsf+WS_AQC)[i]);
    (wsf+WS_BKF)[i] = (0.125f*L2E) * ((wsf+WS_BKM)[i] + (wsf+WS_BKC)[i]);
  }
}

// ---------------- flash-style fused attention, 4-way split-j, exp2 domain ----------------
__global__ __launch_bounds__(256) void k_attn2(float* wsf)
{
  __shared__ float s_bk[SEQ];
  __shared__ float s_ex[4][2][16];
  __shared__ __align__(16) float s_acc[3][64][33];

  const unsigned short* qmh = warr(wsf, A_QMH);
  const unsigned short* qml = warr(wsf, A_QML);
  const unsigned short* sch = warr(wsf, A_SCH);
  const unsigned short* scl = warr(wsf, A_SCL);
  const unsigned short* kmh = warr(wsf, A_KMH);
  const unsigned short* skh = warr(wsf, A_SKH);
  const unsigned short* vmT = warr(wsf, A_VMT);
  const unsigned short* vcT = warr(wsf, A_VCT);
  float* omF = wsf + WS_OM;
  float* ocF = wsf + WS_OC;
  const float* AqF = wsf + WS_AQF;
  const float* BkF = wsf + WS_BKF;

  const int tid = threadIdx.x;
  const int l = tid & 63, li = l & 15, lg = l >> 4;
  const int w = tid >> 6;                    // 0..3
  const int blk = blockIdx.x;                // 0..4095
  const int xcd = blk & 7;
  const int q   = blk >> 3;                  // 0..511
  const int bh  = xcd*16 + (q & 15);
  const int rt  = 31 - (q >> 4);             // row-tile 0..31, heavy first
  const int i = rt*16 + li;
  const int ntile = rt + 1;
  const int qd = ntile >> 2, rr = ntile & 3;
  const int tstart = w*qd + (w < rr ? w : rr);
  const int tend   = tstart + qd + (w < rr ? 1 : 0);
  const float gam = (wsf + WS_GAM)[bh & (NHEAD-1)];   // already *L2E
  const float aq = AqF[(size_t)bh*SEQ + i];

  for (int idx = tid; idx < SEQ; idx += 256) s_bk[idx] = BkF[(size_t)bh*SEQ + idx];

  bf16x8 qf[8];
  {
    const unsigned short* qb[4] = {qmh, qml, sch, scl};
#pragma unroll
    for (int part = 0; part < 2; ++part)
#pragma unroll
      for (int hl = 0; hl < 2; ++hl)
#pragma unroll
        for (int ks = 0; ks < 2; ++ks)
          qf[part*4 + ks*2 + hl] =
            *(const bf16x8*)(qb[part*2+hl] + ((size_t)bh*SEQ + i)*DK + ks*32 + lg*8);
  }
  __syncthreads();

  // scores in log2 domain (Q pre-scaled by 0.25*L2E, Aq/Bk by 0.125*L2E)
  auto score_tile = [&](int t, float* s) {
    const int j0 = t*16;
    f32x4 accA = {0.f,0.f,0.f,0.f};
    f32x4 accB = {0.f,0.f,0.f,0.f};
    const size_t krow = ((size_t)bh*SEQ + j0 + li)*DK + lg*8;
#pragma unroll
    for (int part = 0; part < 2; ++part) {
      const unsigned short* khp = part ? skh : kmh;
#pragma unroll
      for (int ks = 0; ks < 2; ++ks) {
        bf16x8 kh = *(const bf16x8*)(khp + krow + ks*32);
        accA = MFMA32(kh, qf[part*4+ks*2+0], accA);
        accB = MFMA32(kh, qf[part*4+ks*2+1], accB);
      }
    }
    const float4 bk4 = *(const float4*)&s_bk[j0 + lg*4];
    float bks[4] = {bk4.x, bk4.y, bk4.z, bk4.w};
#pragma unroll
    for (int r = 0; r < 4; ++r) {
      int j = j0 + lg*4 + r;
      float v = (accA[r] + accB[r]) - aq - bks[r];
      s[r] = (j > i) ? -3.0e38f : v;
    }
  };

  // ---- pass 1: local stats ----
  float m1 = -3.0e38f, tot = 0.f;
  for (int t = tstart; t < tend; ++t) {
    float s[4]; score_tile(t, s);
    float tm = fmaxf(fmaxf(s[0], s[1]), fmaxf(s[2], s[3]));
    tm = fmaxf(tm, __shfl_xor(tm, 16));
    tm = fmaxf(tm, __shfl_xor(tm, 32));
    float m1n = fmaxf(m1, tm);
    float lsum = exp2f(s[0]-m1n) + exp2f(s[1]-m1n) + exp2f(s[2]-m1n) + exp2f(s[3]-m1n);
    lsum += __shfl_xor(lsum, 16); lsum += __shfl_xor(lsum, 32);
    tot = tot * exp2f(m1 - m1n) + lsum;
    m1 = m1n;
  }
  // ---- 4-way merge of pass-1 stats ----
  if (lg == 0) { s_ex[w][0][li] = m1; s_ex[w][1][li] = tot; }
  __syncthreads();
  float run;
  {
    float mA = s_ex[0][0][li], mB = s_ex[1][0][li],
          mC = s_ex[2][0][li], mD = s_ex[3][0][li];
    float mg = fmaxf(fmaxf(mA, mB), fmaxf(mC, mD));
    float tA = s_ex[0][1][li] * exp2f(mA - mg);
    float tB = s_ex[1][1][li] * exp2f(mB - mg);
    float tC = s_ex[2][1][li] * exp2f(mC - mg);
    float tD = s_ex[3][1][li] * exp2f(mD - mg);
    tot = tA + tB + tC + tD;
    run = (w > 0 ? tA : 0.f) + (w > 1 ? tB : 0.f) + (w > 2 ? tC : 0.f);
    m1 = mg;
  }
  const float invtot = 1.0f / tot;

  // ---- pass 2: scan + online softmax-2 + PV ----
  f32x4 accm[4], accc[4];
  {
    f32x4 z = {0.f,0.f,0.f,0.f};
#pragma unroll
    for (int dt = 0; dt < 4; ++dt) { accm[dt] = z; accc[dt] = z; }
  }
  float m2 = -3.0e38f, sum2 = 0.f;

  auto scan_tile = [&](int t, float* s2) {
    float s[4]; score_tile(t, s);
    float e0 = exp2f(s[0]-m1), e1 = exp2f(s[1]-m1),
          e2 = exp2f(s[2]-m1), e3 = exp2f(s[3]-m1);
    float p0 = e0, p1 = p0+e1, p2 = p1+e2, p3 = p2+e3;
    float lt = p3;
    float a = __shfl_up(lt, 16), b = __shfl_up(lt, 32), c = __shfl_up(lt, 48);
    float excl = (lg >= 1 ? a : 0.f) + (lg >= 2 ? b : 0.f) + (lg >= 3 ? c : 0.f);
    float base = run + excl;
    float cums[4] = {base+p0, base+p1, base+p2, base+p3};
    float ttr = lt;
    ttr += __shfl_xor(ttr, 16); ttr += __shfl_xor(ttr, 32);
    run += ttr;
#pragma unroll
    for (int r = 0; r < 4; ++r) {
      int j = t*16 + lg*4 + r;
      float rem = fmaxf(tot - cums[r], 0.f) * invtot;
      float pos = fmaxf((float)(i - j), 0.f);
      float dist = sqrtf(rem * pos);
      float eff = fmaxf(exp2f(dist * gam), 1e-5f);
      s2[r] = (j > i) ? -3.0e38f : s[r] * eff;
    }
  };

  for (int t0 = tstart; t0 < tend; t0 += 2) {
    float s2A[4], s2B[4];
    scan_tile(t0, s2A);
    const bool hasB = (t0 + 1) < tend;
    if (hasB) scan_tile(t0+1, s2B);
    else { s2B[0]=s2B[1]=s2B[2]=s2B[3] = -3.0e38f; }
    // hoist V loads (independent of p math) to overlap L2 latency
    const int j0A = t0*16;
    const int j0B = hasB ? j0A + 16 : j0A;
    union V16 { struct { uint2 lo, hi; } u; bf16x8 v; };
    V16 vm_[4], vc_[4];
#pragma unroll
    for (int dt = 0; dt < 4; ++dt) {
      const size_t vrow = ((size_t)bh*DK + dt*16 + li)*SEQ;
      vm_[dt].u.lo = *(const uint2*)(vmT + vrow + j0A + lg*4);
      vm_[dt].u.hi = *(const uint2*)(vmT + vrow + j0B + lg*4);
      vc_[dt].u.lo = *(const uint2*)(vcT + vrow + j0A + lg*4);
      vc_[dt].u.hi = *(const uint2*)(vcT + vrow + j0B + lg*4);
    }
    float mt = fmaxf(fmaxf(fmaxf(s2A[0],s2A[1]), fmaxf(s2A[2],s2A[3])),
                     fmaxf(fmaxf(s2B[0],s2B[1]), fmaxf(s2B[2],s2B[3])));
    mt = fmaxf(mt, __shfl_xor(mt, 16));
    mt = fmaxf(mt, __shfl_xor(mt, 32));
    float m2n = fmaxf(m2, mt);
    float scale = exp2f(m2 - m2n);
    float scale2 = scale * scale;
#pragma unroll
    for (int dt = 0; dt < 4; ++dt) { accm[dt] *= scale; accc[dt] *= scale2; }
    float pA[4], pB[4];
#pragma unroll
    for (int r = 0; r < 4; ++r) { pA[r] = exp2f(s2A[r]-m2n); pB[r] = exp2f(s2B[r]-m2n); }
    float ps = pA[0]+pA[1]+pA[2]+pA[3] + pB[0]+pB[1]+pB[2]+pB[3];
    ps += __shfl_xor(ps, 16); ps += __shfl_xor(ps, 32);
    sum2 = sum2 * scale + ps;
    m2 = m2n;
    union PU { uint4 u; bf16x8 v; } pm, pc;
    pm.u.x = pk2bf(pA[0], pA[1]); pm.u.y = pk2bf(pA[2], pA[3]);
    pm.u.z = pk2bf(pB[0], pB[1]); pm.u.w = pk2bf(pB[2], pB[3]);
    pc.u.x = pk2bf(pA[0]*pA[0], pA[1]*pA[1]); pc.u.y = pk2bf(pA[2]*pA[2], pA[3]*pA[3]);
    pc.u.z = pk2bf(pB[0]*pB[0], pB[1]*pB[1]); pc.u.w = pk2bf(pB[2]*pB[2], pB[3]*pB[3]);
#pragma unroll
    for (int dt = 0; dt < 4; ++dt) {
      accm[dt] = MFMA32(vm_[dt].v, pm.v, accm[dt]);
      accc[dt] = MFMA32(vc_[dt].v, pc.v, accc[dt]);
    }
  }

  // ---- 4-way merge of PV state; wave 0 stores ----
  __syncthreads();
  if (lg == 0) s_ex[w][0][li] = m2;
  __syncthreads();
  const float m2g = fmaxf(fmaxf(s_ex[0][0][li], s_ex[1][0][li]),
                          fmaxf(s_ex[2][0][li], s_ex[3][0][li]));
  const float sc = exp2f(m2 - m2g);
  const float sc2 = sc * sc;
  if (w > 0) {
#pragma unroll
    for (int dt = 0; dt < 4; ++dt)
#pragma unroll
      for (int reg = 0; reg < 4; ++reg) {
        s_acc[w-1][l][dt*4 + reg]      = accm[dt][reg] * sc;
        s_acc[w-1][l][16 + dt*4 + reg] = accc[dt][reg] * sc2;
      }
    if (lg == 0) s_ex[w][1][li] = sum2 * sc;
  }
  __syncthreads();
  if (w == 0) {
    const float sum2g = sum2 * sc + s_ex[1][1][li] + s_ex[2][1][li] + s_ex[3][1][li];
    const float inv2 = 1.0f / sum2g;
    const float inv2c = inv2 * inv2;
    const bool zero = (i == 0);
    float* om_p = omF + ((size_t)bh*SEQ + i)*DK;
    float* oc_p = ocF + ((size_t)bh*SEQ + i)*DK;
#pragma unroll
    for (int dt = 0; dt < 4; ++dt) {
      float4 vm4, vc4;
      vm4.x = (accm[dt][0]*sc + s_acc[0][l][dt*4+0] + s_acc[1][l][dt*4+0] + s_acc[2][l][dt*4+0]) * inv2;
      vm4.y = (accm[dt][1]*sc + s_acc[0][l][dt*4+1] + s_acc[1][l][dt*4+1] + s_acc[2][l][dt*4+1]) * inv2;
      vm4.z = (accm[dt][2]*sc + s_acc[0][l][dt*4+2] + s_acc[1][l][dt*4+2] + s_acc[2][l][dt*4+2]) * inv2;
      vm4.w = (accm[dt][3]*sc + s_acc[0][l][dt*4+3] + s_acc[1][l][dt*4+3] + s_acc[2][l][dt*4+3]) * inv2;
      vc4.x = (accc[dt][0]*sc2 + s_acc[0][l][16+dt*4+0] + s_acc[1][l][16+dt*4+0] + s_acc[2][l][16+dt*4+0]) * inv2c;
      vc4.y = (accc[dt][1]*sc2 + s_acc[0][l][16+dt*4+1] + s_acc[1][l][16+dt*4+1] + s_acc[2][l][16+dt*4+1]) * inv2c;
      vc4.z = (accc[dt][2]*sc2 + s_acc[0][l][16+dt*4+2] + s_acc[1][l][16+dt*4+2] + s_acc[2][l][16+dt*4+2]) * inv2c;
      vc4.w = (accc[dt][3]*sc2 + s_acc[0][l][16+dt*4+3] + s_acc[1][l][16+dt*4+3] + s_acc[2][l][16+dt*4+3]) * inv2c;
      if (zero) { vm4 = make_float4(0.f,0.f,0.f,0.f); vc4 = vm4; }
      *(float4*)(om_p + dt*16 + lg*4) = vm4;
      *(float4*)(oc_p + dt*16 + lg*4) = vc4;
    }
  }
}

// ---------------- output GEMM: 1-term bf16 MFMA ----------------
__global__ __launch_bounds__(256) void k_outM(float* wsf,
                                              const float* w_mean, const float* w_cov,
                                              float* outp)
{
  __shared__ __align__(16) unsigned short Ah[4096];
  __shared__ __align__(16) unsigned short Bh[4096];
  const int y = blockIdx.y;
  const float* A = wsf + (y ? WS_OC : WS_OM);
  const float* W = y ? w_cov : w_mean;
  float* out = outp + (size_t)y * 4194304ull;

  const int tid = threadIdx.x;
  const int l = tid & 63, li = l & 15, lg = l >> 4;
  const int w = tid >> 6, wr = w >> 1, wc = w & 1;
  const int blk = blockIdx.x;
  const int xcd = blk & 7, qq = blk >> 3;
  const int m0 = (xcd*8 + (qq & 7)) * 128;
  const int n0 = (qq >> 3) * 128;
  const int r0 = tid >> 2, c0 = tid & 3, r1 = r0 + 64;
  const int wo0 = r0*64 + ((c0 ^ ((r0>>1)&3))*16);
  const int wo1 = r1*64 + ((c0 ^ ((r1>>1)&3))*16);
  int roA[4], roB[4];
#pragma unroll
  for (int mi = 0; mi < 4; ++mi) {
    int r  = wr*64 + mi*16 + li;
    roA[mi] = r*64 + ((lg ^ ((r>>1)&3))*16);
    int rn = wc*64 + mi*16 + li;
    roB[mi] = rn*64 + ((lg ^ ((rn>>1)&3))*16);
  }
  const int mA0 = m0 + r0, mA1 = m0 + r1;
  const size_t abase0 = ((size_t)(mA0 >> 9) * NHEAD * SEQ + (mA0 & 511)) * DK;
  const size_t abase1 = ((size_t)(mA1 >> 9) * NHEAD * SEQ + (mA1 & 511)) * DK;
  const float* wp0 = W + (size_t)(n0 + r0)*DMODEL + c0*8;
  const float* wp1 = W + (size_t)(n0 + r1)*DMODEL + c0*8;

  auto acvt = [&](size_t abase, int k) -> uint4 {
    const float* p = A + abase + (size_t)(k >> 6) * (SEQ*DK) + (k & 63);
    return cvt8h(p);
  };

  int k0 = c0*8;
  uint4 a0 = acvt(abase0, k0);
  uint4 a1 = acvt(abase1, k0);
  uint4 b0 = cvt8h(wp0);
  uint4 b1 = cvt8h(wp1);

  f32x4 acc[4][4];
  f32x4 z = {0.f,0.f,0.f,0.f};
#pragma unroll
  for (int a = 0; a < 4; ++a)
#pragma unroll
    for (int b = 0; b < 4; ++b) acc[a][b] = z;

  for (int kt = 0; kt < DMODEL; kt += 32) {
    __syncthreads();
    *(uint4*)((char*)Ah + wo0) = a0;
    *(uint4*)((char*)Ah + wo1) = a1;
    *(uint4*)((char*)Bh + wo0) = b0;
    *(uint4*)((char*)Bh + wo1) = b1;
    __syncthreads();
    if (kt + 32 < DMODEL) {
      int kn = kt + 32 + c0*8;
      a0 = acvt(abase0, kn);
      a1 = acvt(abase1, kn);
      b0 = cvt8h(wp0 + kt + 32);
      b1 = cvt8h(wp1 + kt + 32);
    }
    bf16x8 ah[4], bh[4];
#pragma unroll
    for (int mi = 0; mi < 4; ++mi) {
      ah[mi] = *(const bf16x8*)((const char*)Ah + roA[mi]);
      bh[mi] = *(const bf16x8*)((const char*)Bh + roB[mi]);
    }
#pragma unroll
    for (int mi = 0; mi < 4; ++mi)
#pragma unroll
      for (int nj = 0; nj < 4; ++nj)
        acc[mi][nj] = MFMA32(ah[mi], bh[nj], acc[mi][nj]);
  }
#pragma unroll
  for (int mi = 0; mi < 4; ++mi)
#pragma unroll
    for (int nj = 0; nj < 4; ++nj)
#pragma unroll
      for (int reg = 0; reg < 4; ++reg) {
        int m = m0 + wr*64 + mi*16 + 4*lg + reg;
        int n = n0 + wc*64 + nj*16 + li;
        out[(size_t)m*DMODEL + n] = acc[mi][nj][reg];
      }
}

extern "C" void kernel_launch(void* const* d_in, const int* in_sizes, int n_in,
                              void* d_out, int out_size, void* d_ws, size_t ws_size,
                              hipStream_t stream) {
  (void)in_sizes; (void)n_in; (void)out_size; (void)ws_size;
  float* wsf = (float*)d_ws;

  k_gamma<<<1, 64, 0, stream>>>((const float*)d_in[14], wsf);
  k_projM<<<dim3(256, 6), 256, 0, stream>>>(
      (const float*)d_in[0], (const float*)d_in[1],
      (const float*)d_in[2], (const float*)d_in[3],
      (const float*)d_in[4], (const float*)d_in[5],
      (const float*)d_in[6], (const float*)d_in[7],
      (const float*)d_in[8], (const float*)d_in[9],
      (const float*)d_in[10], (const float*)d_in[11],
      wsf);
  k_sumAB<<<256, 256, 0, stream>>>(wsf);
  k_attn2<<<4096, 256, 0, stream>>>(wsf);
  k_outM<<<dim3(256, 2), 256, 0, stream>>>(wsf, (const float*)d_in[12],
                                           (const float*)d_in[13], (float*)d_out);
}

// Round 11
// 267.944 us; speedup vs baseline: 1.0009x; 1.0009x over previous
//
#include <hip/hip_runtime.h>
#include <hip/hip_bf16.h>

#define SEQ    512
#define DMODEL 512
#define NHEAD  8
#define DK     64
#define BS     16
#define NBH    (BS*NHEAD)       // 128
#define HSZ    (SEQ*DK)         // 32768 per (b,h)
#define L2E    1.4426950408889634f

typedef __attribute__((ext_vector_type(8))) short bf16x8;
typedef __attribute__((ext_vector_type(4))) float f32x4;

#define MFMA32(A,B,C) __builtin_amdgcn_mfma_f32_16x16x32_bf16(A,B,C,0,0,0)

// ---------------- workspace layout (fp32 units) ----------------
#define WS_GAM 16ull
#define WS_AQM 256ull
#define WS_AQC (WS_AQM +  65536ull)
#define WS_BKM (WS_AQM + 131072ull)
#define WS_BKC (WS_AQM + 196608ull)
#define WS_AQF (WS_AQM + 262144ull)
#define WS_BKF (WS_AQM + 327680ull)
#define WS_OM  1048576ull
#define WS_OC  (WS_OM + 4194304ull)
#define WS_BF  (WS_OC + 4194304ull)     // bf16 arrays region
#define ARRE   4194304ull               // elems per bf16 array
// bf16 array ids
#define A_QMH 0
#define A_QML 1
#define A_SCH 2
#define A_SCL 3
#define A_KMH 4
#define A_SKH 6
#define A_VMT 8
#define A_VCT 9

__device__ __forceinline__ unsigned short* warr(float* wsf, int idx) {
  return (unsigned short*)(wsf + WS_BF) + (size_t)idx * ARRE;
}

// ---------- helpers ----------
__device__ __forceinline__ float bf2f(unsigned short h) {
  union { float f; unsigned u; } v; v.u = ((unsigned)h) << 16; return v.f;
}
__device__ __forceinline__ unsigned short f2bf(float f) {
  union { float f; unsigned u; } v; v.f = f;
  unsigned u = v.u;
  u += 0x7FFFu + ((u >> 16) & 1u);   // RNE
  return (unsigned short)(u >> 16);
}
__device__ __forceinline__ void ld8_f32(const float* p, float* v) {
  float4 a = *(const float4*)p; float4 b = *(const float4*)(p+4);
  v[0]=a.x;v[1]=a.y;v[2]=a.z;v[3]=a.w;v[4]=b.x;v[5]=b.y;v[6]=b.z;v[7]=b.w;
}
// pack 2 fp32 -> [bf16(a) | bf16(b)<<16], round-half-up, via v_perm
__device__ __forceinline__ unsigned pk2bf(float a, float b) {
  union { float f; unsigned u; } x, y;
  x.f = a; y.f = b;
  return __builtin_amdgcn_perm(y.u + 0x8000u, x.u + 0x8000u, 0x07060302u);
}
__device__ __forceinline__ uint4 cvt8r(const float* t8) {
  uint4 h;
  h.x = pk2bf(t8[0], t8[1]);
  h.y = pk2bf(t8[2], t8[3]);
  h.z = pk2bf(t8[4], t8[5]);
  h.w = pk2bf(t8[6], t8[7]);
  return h;
}
__device__ __forceinline__ uint4 cvt8h(const float* p) {
  float t8[8]; ld8_f32(p, t8); return cvt8r(t8);
}

__global__ void k_gamma(const float* __restrict__ g_in, float* __restrict__ wsf) {
  int t = threadIdx.x;
  if (t >= NHEAD) return;
  float g = g_in[t];
  float sp = (g > 20.f) ? g : log1pf(expf(g));
  (wsf + WS_GAM)[t] = -sp * L2E;     // log2 domain
}

// ---------------- projections: 1-term bf16 MFMA (consistent rounding) ----------------
// y: 0 qm, 1 km, 2 qc, 3 kc, 4 vm, 5 vc
__global__ __launch_bounds__(256) void k_projM(
    const float* xqm, const float* xqc, const float* xkm, const float* xkc,
    const float* xvm, const float* xvc,
    const float* wqm, const float* wqc, const float* wkm, const float* wkc,
    const float* wvm, const float* wvc,
    float* wsf)
{
  __shared__ __align__(16) unsigned short Ah[4096];
  __shared__ __align__(16) unsigned short Bh[4096];
  const int y = blockIdx.y;
  const float* X; const float* W;
  unsigned short *outh = nullptr, *outl = nullptr;
  float* sums = nullptr;
  float qscale = 1.0f; int mode = 0;  // 0 mean, 1 cov, 2 v
  switch (y) {
    case 0: X=xqm; W=wqm; outh=warr(wsf,A_QMH); outl=warr(wsf,A_QML); sums=wsf+WS_AQM; qscale=0.25f*L2E; mode=0; break;
    case 1: X=xkm; W=wkm; outh=warr(wsf,A_KMH); outl=nullptr;         sums=wsf+WS_BKM; qscale=1.0f;      mode=0; break;
    case 2: X=xqc; W=wqc; outh=warr(wsf,A_SCH); outl=warr(wsf,A_SCL); sums=wsf+WS_AQC; qscale=0.25f*L2E; mode=1; break;
    case 3: X=xkc; W=wkc; outh=warr(wsf,A_SKH); outl=nullptr;         sums=wsf+WS_BKC; qscale=1.0f;      mode=1; break;
    case 4: X=xvm; W=wvm; outh=warr(wsf,A_VMT); mode=2; break;
    default:X=xvc; W=wvc; outh=warr(wsf,A_VCT); mode=2; break;
  }
  const int tid = threadIdx.x;
  const int l = tid & 63, li = l & 15, lg = l >> 4;
  const int w = tid >> 6, wr = w >> 1, wc = w & 1;
  const int blk = blockIdx.x;
  const int xcd = blk & 7, qq = blk >> 3;           // qq 0..31
  const int m0 = (xcd*8 + (qq & 7)) * 128;
  const int n0 = (qq >> 3) * 128;
  const int r0 = tid >> 2, c0 = tid & 3, r1 = r0 + 64;
  const int wo0 = r0*64 + ((c0 ^ ((r0>>1)&3))*16);
  const int wo1 = r1*64 + ((c0 ^ ((r1>>1)&3))*16);
  int roA[4], roB[4];
#pragma unroll
  for (int mi = 0; mi < 4; ++mi) {
    int r  = wr*64 + mi*16 + li;
    roA[mi] = r*64 + ((lg ^ ((r>>1)&3))*16);
    int rn = wc*64 + mi*16 + li;
    roB[mi] = rn*64 + ((lg ^ ((rn>>1)&3))*16);
  }
  const float* xp0 = X + (size_t)(m0+r0)*DMODEL + c0*8;
  const float* xp1 = X + (size_t)(m0+r1)*DMODEL + c0*8;
  const float* wp0 = W + (size_t)(n0+r0)*DMODEL + c0*8;
  const float* wp1 = W + (size_t)(n0+r1)*DMODEL + c0*8;
  uint4 a0 = cvt8h(xp0);
  uint4 a1 = cvt8h(xp1);
  uint4 b0 = cvt8h(wp0);
  uint4 b1 = cvt8h(wp1);

  f32x4 acc[4][4];
  f32x4 z = {0.f,0.f,0.f,0.f};
#pragma unroll
  for (int a = 0; a < 4; ++a)
#pragma unroll
    for (int b = 0; b < 4; ++b) acc[a][b] = z;

  for (int kt = 0; kt < DMODEL; kt += 32) {
    __syncthreads();
    *(uint4*)((char*)Ah + wo0) = a0;
    *(uint4*)((char*)Ah + wo1) = a1;
    *(uint4*)((char*)Bh + wo0) = b0;
    *(uint4*)((char*)Bh + wo1) = b1;
    __syncthreads();
    if (kt + 32 < DMODEL) {
      a0 = cvt8h(xp0 + kt + 32);
      a1 = cvt8h(xp1 + kt + 32);
      b0 = cvt8h(wp0 + kt + 32);
      b1 = cvt8h(wp1 + kt + 32);
    }
    bf16x8 ah[4], bh[4];
#pragma unroll
    for (int mi = 0; mi < 4; ++mi) {
      ah[mi] = *(const bf16x8*)((const char*)Ah + roA[mi]);
      bh[mi] = *(const bf16x8*)((const char*)Bh + roB[mi]);
    }
#pragma unroll
    for (int mi = 0; mi < 4; ++mi)
#pragma unroll
      for (int nj = 0; nj < 4; ++nj)
        acc[mi][nj] = MFMA32(ah[mi], bh[nj], acc[mi][nj]);
  }

  const int head = ((n0 >> 6) + wc);
  if (mode <= 1) {
    const bool kside = (outl == nullptr);
#pragma unroll
    for (int mi = 0; mi < 4; ++mi)
#pragma unroll
      for (int reg = 0; reg < 4; ++reg) {
        float rs = 0.f;
#pragma unroll
        for (int nj = 0; nj < 4; ++nj) {
          float v = acc[mi][nj][reg];
          if (mode == 0) {
            float vs = (kside) ? bf2f(f2bf(v)) : v;   // consistent with stored K
            rs += vs*vs;
          } else {
            rs += v;                                   // raw cov sum (reference semantics)
          }
        }
        rs += __shfl_xor(rs, 1); rs += __shfl_xor(rs, 2);
        rs += __shfl_xor(rs, 4); rs += __shfl_xor(rs, 8);
        if (li == 0) {
          int m = m0 + wr*64 + mi*16 + 4*lg + reg;
          sums[((size_t)(m >> 9)*NHEAD + head)*SEQ + (m & 511)] = rs;
        }
      }
#pragma unroll
    for (int mi = 0; mi < 4; ++mi)
#pragma unroll
      for (int nj = 0; nj < 4; ++nj)
#pragma unroll
        for (int reg = 0; reg < 4; ++reg) {
          float v = acc[mi][nj][reg];
          if (mode == 1) v = sqrtf(fmaxf(v, 1e-24f));
          v *= qscale;
          unsigned short h16 = f2bf(v);
          int m = m0 + wr*64 + mi*16 + 4*lg + reg;
          int n = n0 + wc*64 + nj*16 + li;
          size_t dst = ((size_t)((m >> 9)*NHEAD + (n >> 6))*SEQ + (m & 511))*DK + (n & 63);
          outh[dst] = h16;
          if (outl) outl[dst] = f2bf(v - bf2f(h16));
        }
  } else {
    // V: transposed [bh][d][s], 4 consecutive s per store
#pragma unroll
    for (int mi = 0; mi < 4; ++mi)
#pragma unroll
      for (int nj = 0; nj < 4; ++nj) {
        int mb = m0 + wr*64 + mi*16 + 4*lg;
        int n = n0 + wc*64 + nj*16 + li;
        int b = mb >> 9, s = mb & 511, d = n & 63;
        unsigned e0 = f2bf(acc[mi][nj][0]);
        unsigned e1 = f2bf(acc[mi][nj][1]);
        unsigned e2 = f2bf(acc[mi][nj][2]);
        unsigned e3 = f2bf(acc[mi][nj][3]);
        uint2 pk; pk.x = e0 | (e1 << 16); pk.y = e2 | (e3 << 16);
        *(uint2*)(outh + ((size_t)(b*NHEAD + head)*DK + d)*SEQ + s) = pk;
      }
  }
}

__global__ void k_sumAB(float* wsf) {
  int i = blockIdx.x * 256 + threadIdx.x;
  if (i < NBH*SEQ) {
    (wsf+WS_AQF)[i] = (0.125f*L2E) * ((wsf+WS_AQM)[i] + (wsf+WS_AQC)[i]);
    (wsf+WS_BKF)[i] = (0.125f*L2E) * ((wsf+WS_BKM)[i] + (wsf+WS_BKC)[i]);
  }
}

// ---------------- flash-style fused attention, 4-way split-j, exp2 domain ----------------
__global__ __launch_bounds__(256) void k_attn2(float* wsf)
{
  __shared__ float s_bk[SEQ];
  __shared__ float s_ex[4][2][16];
  __shared__ __align__(16) float s_acc[3][64][33];

  const unsigned short* qmh = warr(wsf, A_QMH);
  const unsigned short* qml = warr(wsf, A_QML);
  const unsigned short* sch = warr(wsf, A_SCH);
  const unsigned short* scl = warr(wsf, A_SCL);
  const unsigned short* kmh = warr(wsf, A_KMH);
  const unsigned short* skh = warr(wsf, A_SKH);
  const unsigned short* vmT = warr(wsf, A_VMT);
  const unsigned short* vcT = warr(wsf, A_VCT);
  float* omF = wsf + WS_OM;
  float* ocF = wsf + WS_OC;
  const float* AqF = wsf + WS_AQF;
  const float* BkF = wsf + WS_BKF;

  const int tid = threadIdx.x;
  const int l = tid & 63, li = l & 15, lg = l >> 4;
  const int w = tid >> 6;                    // 0..3
  const int blk = blockIdx.x;                // 0..4095
  const int xcd = blk & 7;
  const int q   = blk >> 3;                  // 0..511
  const int bh  = xcd*16 + (q & 15);
  const int rt  = 31 - (q >> 4);             // row-tile 0..31, heavy first
  const int i = rt*16 + li;
  const int ntile = rt + 1;
  const int qd = ntile >> 2, rr = ntile & 3;
  const int tstart = w*qd + (w < rr ? w : rr);
  const int tend   = tstart + qd + (w < rr ? 1 : 0);
  const float gam = (wsf + WS_GAM)[bh & (NHEAD-1)];   // already *L2E
  const float aq = AqF[(size_t)bh*SEQ + i];

  for (int idx = tid; idx < SEQ; idx += 256) s_bk[idx] = BkF[(size_t)bh*SEQ + idx];

  bf16x8 qf[8];
  {
    const unsigned short* qb[4] = {qmh, qml, sch, scl};
#pragma unroll
    for (int part = 0; part < 2; ++part)
#pragma unroll
      for (int hl = 0; hl < 2; ++hl)
#pragma unroll
        for (int ks = 0; ks < 2; ++ks)
          qf[part*4 + ks*2 + hl] =
            *(const bf16x8*)(qb[part*2+hl] + ((size_t)bh*SEQ + i)*DK + ks*32 + lg*8);
  }
  __syncthreads();

  // scores in log2 domain (Q pre-scaled by 0.25*L2E, Aq/Bk by 0.125*L2E)
  auto score_tile = [&](int t, float* s) {
    const int j0 = t*16;
    f32x4 accA = {0.f,0.f,0.f,0.f};
    f32x4 accB = {0.f,0.f,0.f,0.f};
    const size_t krow = ((size_t)bh*SEQ + j0 + li)*DK + lg*8;
#pragma unroll
    for (int part = 0; part < 2; ++part) {
      const unsigned short* khp = part ? skh : kmh;
#pragma unroll
      for (int ks = 0; ks < 2; ++ks) {
        bf16x8 kh = *(const bf16x8*)(khp + krow + ks*32);
        accA = MFMA32(kh, qf[part*4+ks*2+0], accA);
        accB = MFMA32(kh, qf[part*4+ks*2+1], accB);
      }
    }
    const float4 bk4 = *(const float4*)&s_bk[j0 + lg*4];
    float bks[4] = {bk4.x, bk4.y, bk4.z, bk4.w};
#pragma unroll
    for (int r = 0; r < 4; ++r) {
      int j = j0 + lg*4 + r;
      float v = (accA[r] + accB[r]) - aq - bks[r];
      s[r] = (j > i) ? -3.0e38f : v;
    }
  };

  // ---- pass 1: local stats ----
  float m1 = -3.0e38f, tot = 0.f;
  for (int t = tstart; t < tend; ++t) {
    float s[4]; score_tile(t, s);
    float tm = fmaxf(fmaxf(s[0], s[1]), fmaxf(s[2], s[3]));
    tm = fmaxf(tm, __shfl_xor(tm, 16));
    tm = fmaxf(tm, __shfl_xor(tm, 32));
    float m1n = fmaxf(m1, tm);
    float lsum = exp2f(s[0]-m1n) + exp2f(s[1]-m1n) + exp2f(s[2]-m1n) + exp2f(s[3]-m1n);
    lsum += __shfl_xor(lsum, 16); lsum += __shfl_xor(lsum, 32);
    tot = tot * exp2f(m1 - m1n) + lsum;
    m1 = m1n;
  }
  // ---- 4-way merge of pass-1 stats ----
  if (lg == 0) { s_ex[w][0][li] = m1; s_ex[w][1][li] = tot; }
  __syncthreads();
  float run;
  {
    float mA = s_ex[0][0][li], mB = s_ex[1][0][li],
          mC = s_ex[2][0][li], mD = s_ex[3][0][li];
    float mg = fmaxf(fmaxf(mA, mB), fmaxf(mC, mD));
    float tA = s_ex[0][1][li] * exp2f(mA - mg);
    float tB = s_ex[1][1][li] * exp2f(mB - mg);
    float tC = s_ex[2][1][li] * exp2f(mC - mg);
    float tD = s_ex[3][1][li] * exp2f(mD - mg);
    tot = tA + tB + tC + tD;
    run = (w > 0 ? tA : 0.f) + (w > 1 ? tB : 0.f) + (w > 2 ? tC : 0.f);
    m1 = mg;
  }
  const float invtot = 1.0f / tot;

  // ---- pass 2: scan + online softmax-2 + PV ----
  f32x4 accm[4], accc[4];
  {
    f32x4 z = {0.f,0.f,0.f,0.f};
#pragma unroll
    for (int dt = 0; dt < 4; ++dt) { accm[dt] = z; accc[dt] = z; }
  }
  float m2 = -3.0e38f, sum2 = 0.f;

  auto scan_tile = [&](int t, float* s2) {
    float s[4]; score_tile(t, s);
    float e0 = exp2f(s[0]-m1), e1 = exp2f(s[1]-m1),
          e2 = exp2f(s[2]-m1), e3 = exp2f(s[3]-m1);
    float p0 = e0, p1 = p0+e1, p2 = p1+e2, p3 = p2+e3;
    float lt = p3;
    float a = __shfl_up(lt, 16), b = __shfl_up(lt, 32), c = __shfl_up(lt, 48);
    float excl = (lg >= 1 ? a : 0.f) + (lg >= 2 ? b : 0.f) + (lg >= 3 ? c : 0.f);
    float base = run + excl;
    float cums[4] = {base+p0, base+p1, base+p2, base+p3};
    float ttr = lt;
    ttr += __shfl_xor(ttr, 16); ttr += __shfl_xor(ttr, 32);
    run += ttr;
#pragma unroll
    for (int r = 0; r < 4; ++r) {
      int j = t*16 + lg*4 + r;
      float rem = fmaxf(tot - cums[r], 0.f) * invtot;
      float pos = fmaxf((float)(i - j), 0.f);
      float dist = sqrtf(rem * pos);
      float eff = fmaxf(exp2f(dist * gam), 1e-5f);
      s2[r] = (j > i) ? -3.0e38f : s[r] * eff;
    }
  };

  for (int t0 = tstart; t0 < tend; t0 += 2) {
    float s2A[4], s2B[4];
    scan_tile(t0, s2A);
    const bool hasB = (t0 + 1) < tend;
    if (hasB) scan_tile(t0+1, s2B);
    else { s2B[0]=s2B[1]=s2B[2]=s2B[3] = -3.0e38f; }
    // hoist V loads (independent of p math) to overlap L2 latency
    const int j0A = t0*16;
    const int j0B = hasB ? j0A + 16 : j0A;
    union V16 { struct { uint2 lo, hi; } u; bf16x8 v; };
    V16 vm_[4], vc_[4];
#pragma unroll
    for (int dt = 0; dt < 4; ++dt) {
      const size_t vrow = ((size_t)bh*DK + dt*16 + li)*SEQ;
      vm_[dt].u.lo = *(const uint2*)(vmT + vrow + j0A + lg*4);
      vm_[dt].u.hi = *(const uint2*)(vmT + vrow + j0B + lg*4);
      vc_[dt].u.lo = *(const uint2*)(vcT + vrow + j0A + lg*4);
      vc_[dt].u.hi = *(const uint2*)(vcT + vrow + j0B + lg*4);
    }
    float mt = fmaxf(fmaxf(fmaxf(s2A[0],s2A[1]), fmaxf(s2A[2],s2A[3])),
                     fmaxf(fmaxf(s2B[0],s2B[1]), fmaxf(s2B[2],s2B[3])));
    mt = fmaxf(mt, __shfl_xor(mt, 16));
    mt = fmaxf(mt, __shfl_xor(mt, 32));
    float m2n = fmaxf(m2, mt);
    float scale = exp2f(m2 - m2n);
    float scale2 = scale * scale;
#pragma unroll
    for (int dt = 0; dt < 4; ++dt) { accm[dt] *= scale; accc[dt] *= scale2; }
    float pA[4], pB[4];
#pragma unroll
    for (int r = 0; r < 4; ++r) { pA[r] = exp2f(s2A[r]-m2n); pB[r] = exp2f(s2B[r]-m2n); }
    float ps = pA[0]+pA[1]+pA[2]+pA[3] + pB[0]+pB[1]+pB[2]+pB[3];
    ps += __shfl_xor(ps, 16); ps += __shfl_xor(ps, 32);
    sum2 = sum2 * scale + ps;
    m2 = m2n;
    union PU { uint4 u; bf16x8 v; } pm, pc;
    pm.u.x = pk2bf(pA[0], pA[1]); pm.u.y = pk2bf(pA[2], pA[3]);
    pm.u.z = pk2bf(pB[0], pB[1]); pm.u.w = pk2bf(pB[2], pB[3]);
    pc.u.x = pk2bf(pA[0]*pA[0], pA[1]*pA[1]); pc.u.y = pk2bf(pA[2]*pA[2], pA[3]*pA[3]);
    pc.u.z = pk2bf(pB[0]*pB[0], pB[1]*pB[1]); pc.u.w = pk2bf(pB[2]*pB[2], pB[3]*pB[3]);
#pragma unroll
    for (int dt = 0; dt < 4; ++dt) {
      accm[dt] = MFMA32(vm_[dt].v, pm.v, accm[dt]);
      accc[dt] = MFMA32(vc_[dt].v, pc.v, accc[dt]);
    }
  }

  // ---- 4-way merge of PV state; wave 0 stores ----
  __syncthreads();
  if (lg == 0) s_ex[w][0][li] = m2;
  __syncthreads();
  const float m2g = fmaxf(fmaxf(s_ex[0][0][li], s_ex[1][0][li]),
                          fmaxf(s_ex[2][0][li], s_ex[3][0][li]));
  const float sc = exp2f(m2 - m2g);
  const float sc2 = sc * sc;
  if (w > 0) {
#pragma unroll
    for (int dt = 0; dt < 4; ++dt)
#pragma unroll
      for (int reg = 0; reg < 4; ++reg) {
        s_acc[w-1][l][dt*4 + reg]      = accm[dt][reg] * sc;
        s_acc[w-1][l][16 + dt*4 + reg] = accc[dt][reg] * sc2;
      }
    if (lg == 0) s_ex[w][1][li] = sum2 * sc;
  }
  __syncthreads();
  if (w == 0) {
    const float sum2g = sum2 * sc + s_ex[1][1][li] + s_ex[2][1][li] + s_ex[3][1][li];
    const float inv2 = 1.0f / sum2g;
    const float inv2c = inv2 * inv2;
    const bool zero = (i == 0);
    float* om_p = omF + ((size_t)bh*SEQ + i)*DK;
    float* oc_p = ocF + ((size_t)bh*SEQ + i)*DK;
#pragma unroll
    for (int dt = 0; dt < 4; ++dt) {
      float4 vm4, vc4;
      vm4.x = (accm[dt][0]*sc + s_acc[0][l][dt*4+0] + s_acc[1][l][dt*4+0] + s_acc[2][l][dt*4+0]) * inv2;
      vm4.y = (accm[dt][1]*sc + s_acc[0][l][dt*4+1] + s_acc[1][l][dt*4+1] + s_acc[2][l][dt*4+1]) * inv2;
      vm4.z = (accm[dt][2]*sc + s_acc[0][l][dt*4+2] + s_acc[1][l][dt*4+2] + s_acc[2][l][dt*4+2]) * inv2;
      vm4.w = (accm[dt][3]*sc + s_acc[0][l][dt*4+3] + s_acc[1][l][dt*4+3] + s_acc[2][l][dt*4+3]) * inv2;
      vc4.x = (accc[dt][0]*sc2 + s_acc[0][l][16+dt*4+0] + s_acc[1][l][16+dt*4+0] + s_acc[2][l][16+dt*4+0]) * inv2c;
      vc4.y = (accc[dt][1]*sc2 + s_acc[0][l][16+dt*4+1] + s_acc[1][l][16+dt*4+1] + s_acc[2][l][16+dt*4+1]) * inv2c;
      vc4.z = (accc[dt][2]*sc2 + s_acc[0][l][16+dt*4+2] + s_acc[1][l][16+dt*4+2] + s_acc[2][l][16+dt*4+2]) * inv2c;
      vc4.w = (accc[dt][3]*sc2 + s_acc[0][l][16+dt*4+3] + s_acc[1][l][16+dt*4+3] + s_acc[2][l][16+dt*4+3]) * inv2c;
      if (zero) { vm4 = make_float4(0.f,0.f,0.f,0.f); vc4 = vm4; }
      *(float4*)(om_p + dt*16 + lg*4) = vm4;
      *(float4*)(oc_p + dt*16 + lg*4) = vc4;
    }
  }
}

// ---------------- output GEMM: 1-term bf16 MFMA ----------------
__global__ __launch_bounds__(256) void k_outM(float* wsf,
                                              const float* w_mean, const float* w_cov,
                                              float* outp)
{
  __shared__ __align__(16) unsigned short Ah[4096];
  __shared__ __align__(16) unsigned short Bh[4096];
  const int y = blockIdx.y;
  const float* A = wsf + (y ? WS_OC : WS_OM);
  const float* W = y ? w_cov : w_mean;
  float* out = outp + (size_t)y * 4194304ull;

  const int tid = threadIdx.x;
  const int l = tid & 63, li = l & 15, lg = l >> 4;
  const int w = tid >> 6, wr = w >> 1, wc = w & 1;
  const int blk = blockIdx.x;
  const int xcd = blk & 7, qq = blk >> 3;
  const int m0 = (xcd*8 + (qq & 7)) * 128;
  const int n0 = (qq >> 3) * 128;
  const int r0 = tid >> 2, c0 = tid & 3, r1 = r0 + 64;
  const int wo0 = r0*64 + ((c0 ^ ((r0>>1)&3))*16);
  const int wo1 = r1*64 + ((c0 ^ ((r1>>1)&3))*16);
  int roA[4], roB[4];
#pragma unroll
  for (int mi = 0; mi < 4; ++mi) {
    int r  = wr*64 + mi*16 + li;
    roA[mi] = r*64 + ((lg ^ ((r>>1)&3))*16);
    int rn = wc*64 + mi*16 + li;
    roB[mi] = rn*64 + ((lg ^ ((rn>>1)&3))*16);
  }
  const int mA0 = m0 + r0, mA1 = m0 + r1;
  const size_t abase0 = ((size_t)(mA0 >> 9) * NHEAD * SEQ + (mA0 & 511)) * DK;
  const size_t abase1 = ((size_t)(mA1 >> 9) * NHEAD * SEQ + (mA1 & 511)) * DK;
  const float* wp0 = W + (size_t)(n0 + r0)*DMODEL + c0*8;
  const float* wp1 = W + (size_t)(n0 + r1)*DMODEL + c0*8;

  auto acvt = [&](size_t abase, int k) -> uint4 {
    const float* p = A + abase + (size_t)(k >> 6) * (SEQ*DK) + (k & 63);
    return cvt8h(p);
  };

  int k0 = c0*8;
  uint4 a0 = acvt(abase0, k0);
  uint4 a1 = acvt(abase1, k0);
  uint4 b0 = cvt8h(wp0);
  uint4 b1 = cvt8h(wp1);

  f32x4 acc[4][4];
  f32x4 z = {0.f,0.f,0.f,0.f};
#pragma unroll
  for (int a = 0; a < 4; ++a)
#pragma unroll
    for (int b = 0; b < 4; ++b) acc[a][b] = z;

  for (int kt = 0; kt < DMODEL; kt += 32) {
    __syncthreads();
    *(uint4*)((char*)Ah + wo0) = a0;
    *(uint4*)((char*)Ah + wo1) = a1;
    *(uint4*)((char*)Bh + wo0) = b0;
    *(uint4*)((char*)Bh + wo1) = b1;
    __syncthreads();
    if (kt + 32 < DMODEL) {
      int kn = kt + 32 + c0*8;
      a0 = acvt(abase0, kn);
      a1 = acvt(abase1, kn);
      b0 = cvt8h(wp0 + kt + 32);
      b1 = cvt8h(wp1 + kt + 32);
    }
    bf16x8 ah[4], bh[4];
#pragma unroll
    for (int mi = 0; mi < 4; ++mi) {
      ah[mi] = *(const bf16x8*)((const char*)Ah + roA[mi]);
      bh[mi] = *(const bf16x8*)((const char*)Bh + roB[mi]);
    }
#pragma unroll
    for (int mi = 0; mi < 4; ++mi)
#pragma unroll
      for (int nj = 0; nj < 4; ++nj)
        acc[mi][nj] = MFMA32(ah[mi], bh[nj], acc[mi][nj]);
  }
#pragma unroll
  for (int mi = 0; mi < 4; ++mi)
#pragma unroll
    for (int nj = 0; nj < 4; ++nj)
#pragma unroll
      for (int reg = 0; reg < 4; ++reg) {
        int m = m0 + wr*64 + mi*16 + 4*lg + reg;
        int n = n0 + wc*64 + nj*16 + li;
        out[(size_t)m*DMODEL + n] = acc[mi][nj][reg];
      }
}

extern "C" void kernel_launch(void* const* d_in, const int* in_sizes, int n_in,
                              void* d_out, int out_size, void* d_ws, size_t ws_size,
                              hipStream_t stream) {
  (void)in_sizes; (void)n_in; (void)out_size; (void)ws_size;
  float* wsf = (float*)d_ws;

  k_gamma<<<1, 64, 0, stream>>>((const float*)d_in[14], wsf);
  k_projM<<<dim3(256, 6), 256, 0, stream>>>(
      (const float*)d_in[0], (const float*)d_in[1],
      (const float*)d_in[2], (const float*)d_in[3],
      (const float*)d_in[4], (const float*)d_in[5],
      (const float*)d_in[6], (const float*)d_in[7],
      (const float*)d_in[8], (const float*)d_in[9],
      (const float*)d_in[10], (const float*)d_in[11],
      wsf);
  k_sumAB<<<256, 256, 0, stream>>>(wsf);
  k_attn2<<<4096, 256, 0, stream>>>(wsf);
  k_outM<<<dim3(256, 2), 256, 0, stream>>>(wsf, (const float*)d_in[12],
                                           (const float*)d_in[13], (float*)d_out);
}

// Round 12
// 241.029 us; speedup vs baseline: 1.1127x; 1.1117x over previous
//
#include <hip/hip_runtime.h>
#include <hip/hip_bf16.h>

#define SEQ    512
#define DMODEL 512
#define NHEAD  8
#define DK     64
#define BS     16
#define NBH    (BS*NHEAD)       // 128
#define HSZ    (SEQ*DK)         // 32768 per (b,h)
#define L2E    1.4426950408889634f

typedef __attribute__((ext_vector_type(8))) short bf16x8;
typedef __attribute__((ext_vector_type(4))) float f32x4;

#define MFMA32(A,B,C) __builtin_amdgcn_mfma_f32_16x16x32_bf16(A,B,C,0,0,0)

// ---------------- workspace layout (fp32 units) ----------------
#define WS_GAM 16ull
#define WS_AQM 256ull
#define WS_AQC (WS_AQM +  65536ull)
#define WS_BKM (WS_AQM + 131072ull)
#define WS_BKC (WS_AQM + 196608ull)
#define WS_AQF (WS_AQM + 262144ull)
#define WS_BKF (WS_AQM + 327680ull)
#define WS_OM  1048576ull
#define WS_OC  (WS_OM + 4194304ull)
#define WS_BF  (WS_OC + 4194304ull)     // bf16 arrays region
#define ARRE   4194304ull               // elems per bf16 array
// bf16 array ids
#define A_QMH 0
#define A_QML 1
#define A_SCH 2
#define A_SCL 3
#define A_KMH 4
#define A_SKH 6
#define A_VMT 8
#define A_VCT 9

__device__ __forceinline__ unsigned short* warr(float* wsf, int idx) {
  return (unsigned short*)(wsf + WS_BF) + (size_t)idx * ARRE;
}

// ---------- helpers ----------
__device__ __forceinline__ float bf2f(unsigned short h) {
  union { float f; unsigned u; } v; v.u = ((unsigned)h) << 16; return v.f;
}
__device__ __forceinline__ unsigned short f2bf(float f) {
  union { float f; unsigned u; } v; v.f = f;
  unsigned u = v.u;
  u += 0x7FFFu + ((u >> 16) & 1u);   // RNE
  return (unsigned short)(u >> 16);
}
__device__ __forceinline__ void ld8_f32(const float* p, float* v) {
  float4 a = *(const float4*)p; float4 b = *(const float4*)(p+4);
  v[0]=a.x;v[1]=a.y;v[2]=a.z;v[3]=a.w;v[4]=b.x;v[5]=b.y;v[6]=b.z;v[7]=b.w;
}
// pack 2 fp32 -> [bf16(a) | bf16(b)<<16], round-half-up, via v_perm
__device__ __forceinline__ unsigned pk2bf(float a, float b) {
  union { float f; unsigned u; } x, y;
  x.f = a; y.f = b;
  return __builtin_amdgcn_perm(y.u + 0x8000u, x.u + 0x8000u, 0x07060302u);
}
__device__ __forceinline__ uint4 cvt8r(const float* t8) {
  uint4 h;
  h.x = pk2bf(t8[0], t8[1]);
  h.y = pk2bf(t8[2], t8[3]);
  h.z = pk2bf(t8[4], t8[5]);
  h.w = pk2bf(t8[6], t8[7]);
  return h;
}
__device__ __forceinline__ uint4 cvt8h(const float* p) {
  float t8[8]; ld8_f32(p, t8); return cvt8r(t8);
}

__global__ void k_gamma(const float* __restrict__ g_in, float* __restrict__ wsf) {
  int t = threadIdx.x;
  if (t >= NHEAD) return;
  float g = g_in[t];
  float sp = (g > 20.f) ? g : log1pf(expf(g));
  float gl = sp * L2E;                 // |gamma| in log2 domain
  (wsf + WS_GAM)[t] = gl * gl;         // store gamma^2 (log2 domain)
}

// ---------------- projections: 1-term bf16 MFMA (consistent rounding) ----------------
// y: 0 qm, 1 km, 2 qc, 3 kc, 4 vm, 5 vc
__global__ __launch_bounds__(256) void k_projM(
    const float* xqm, const float* xqc, const float* xkm, const float* xkc,
    const float* xvm, const float* xvc,
    const float* wqm, const float* wqc, const float* wkm, const float* wkc,
    const float* wvm, const float* wvc,
    float* wsf)
{
  __shared__ __align__(16) unsigned short Ah[4096];
  __shared__ __align__(16) unsigned short Bh[4096];
  const int y = blockIdx.y;
  const float* X; const float* W;
  unsigned short *outh = nullptr, *outl = nullptr;
  float* sums = nullptr;
  float qscale = 1.0f; int mode = 0;  // 0 mean, 1 cov, 2 v
  switch (y) {
    case 0: X=xqm; W=wqm; outh=warr(wsf,A_QMH); outl=warr(wsf,A_QML); sums=wsf+WS_AQM; qscale=0.25f*L2E; mode=0; break;
    case 1: X=xkm; W=wkm; outh=warr(wsf,A_KMH); outl=nullptr;         sums=wsf+WS_BKM; qscale=1.0f;      mode=0; break;
    case 2: X=xqc; W=wqc; outh=warr(wsf,A_SCH); outl=warr(wsf,A_SCL); sums=wsf+WS_AQC; qscale=0.25f*L2E; mode=1; break;
    case 3: X=xkc; W=wkc; outh=warr(wsf,A_SKH); outl=nullptr;         sums=wsf+WS_BKC; qscale=1.0f;      mode=1; break;
    case 4: X=xvm; W=wvm; outh=warr(wsf,A_VMT); mode=2; break;
    default:X=xvc; W=wvc; outh=warr(wsf,A_VCT); mode=2; break;
  }
  const int tid = threadIdx.x;
  const int l = tid & 63, li = l & 15, lg = l >> 4;
  const int w = tid >> 6, wr = w >> 1, wc = w & 1;
  const int blk = blockIdx.x;
  const int xcd = blk & 7, qq = blk >> 3;           // qq 0..31
  const int m0 = (xcd*8 + (qq & 7)) * 128;
  const int n0 = (qq >> 3) * 128;
  const int r0 = tid >> 2, c0 = tid & 3, r1 = r0 + 64;
  const int wo0 = r0*64 + ((c0 ^ ((r0>>1)&3))*16);
  const int wo1 = r1*64 + ((c0 ^ ((r1>>1)&3))*16);
  int roA[4], roB[4];
#pragma unroll
  for (int mi = 0; mi < 4; ++mi) {
    int r  = wr*64 + mi*16 + li;
    roA[mi] = r*64 + ((lg ^ ((r>>1)&3))*16);
    int rn = wc*64 + mi*16 + li;
    roB[mi] = rn*64 + ((lg ^ ((rn>>1)&3))*16);
  }
  const float* xp0 = X + (size_t)(m0+r0)*DMODEL + c0*8;
  const float* xp1 = X + (size_t)(m0+r1)*DMODEL + c0*8;
  const float* wp0 = W + (size_t)(n0+r0)*DMODEL + c0*8;
  const float* wp1 = W + (size_t)(n0+r1)*DMODEL + c0*8;
  uint4 a0 = cvt8h(xp0);
  uint4 a1 = cvt8h(xp1);
  uint4 b0 = cvt8h(wp0);
  uint4 b1 = cvt8h(wp1);

  f32x4 acc[4][4];
  f32x4 z = {0.f,0.f,0.f,0.f};
#pragma unroll
  for (int a = 0; a < 4; ++a)
#pragma unroll
    for (int b = 0; b < 4; ++b) acc[a][b] = z;

  for (int kt = 0; kt < DMODEL; kt += 32) {
    __syncthreads();
    *(uint4*)((char*)Ah + wo0) = a0;
    *(uint4*)((char*)Ah + wo1) = a1;
    *(uint4*)((char*)Bh + wo0) = b0;
    *(uint4*)((char*)Bh + wo1) = b1;
    __syncthreads();
    if (kt + 32 < DMODEL) {
      a0 = cvt8h(xp0 + kt + 32);
      a1 = cvt8h(xp1 + kt + 32);
      b0 = cvt8h(wp0 + kt + 32);
      b1 = cvt8h(wp1 + kt + 32);
    }
    bf16x8 ah[4], bh[4];
#pragma unroll
    for (int mi = 0; mi < 4; ++mi) {
      ah[mi] = *(const bf16x8*)((const char*)Ah + roA[mi]);
      bh[mi] = *(const bf16x8*)((const char*)Bh + roB[mi]);
    }
#pragma unroll
    for (int mi = 0; mi < 4; ++mi)
#pragma unroll
      for (int nj = 0; nj < 4; ++nj)
        acc[mi][nj] = MFMA32(ah[mi], bh[nj], acc[mi][nj]);
  }

  const int head = ((n0 >> 6) + wc);
  if (mode <= 1) {
    const bool kside = (outl == nullptr);
#pragma unroll
    for (int mi = 0; mi < 4; ++mi)
#pragma unroll
      for (int reg = 0; reg < 4; ++reg) {
        float rs = 0.f;
#pragma unroll
        for (int nj = 0; nj < 4; ++nj) {
          float v = acc[mi][nj][reg];
          if (mode == 0) {
            float vs = (kside) ? bf2f(f2bf(v)) : v;   // consistent with stored K
            rs += vs*vs;
          } else {
            rs += v;                                   // raw cov sum (reference semantics)
          }
        }
        rs += __shfl_xor(rs, 1); rs += __shfl_xor(rs, 2);
        rs += __shfl_xor(rs, 4); rs += __shfl_xor(rs, 8);
        if (li == 0) {
          int m = m0 + wr*64 + mi*16 + 4*lg + reg;
          sums[((size_t)(m >> 9)*NHEAD + head)*SEQ + (m & 511)] = rs;
        }
      }
#pragma unroll
    for (int mi = 0; mi < 4; ++mi)
#pragma unroll
      for (int nj = 0; nj < 4; ++nj)
#pragma unroll
        for (int reg = 0; reg < 4; ++reg) {
          float v = acc[mi][nj][reg];
          if (mode == 1) v = sqrtf(fmaxf(v, 1e-24f));
          v *= qscale;
          unsigned short h16 = f2bf(v);
          int m = m0 + wr*64 + mi*16 + 4*lg + reg;
          int n = n0 + wc*64 + nj*16 + li;
          size_t dst = ((size_t)((m >> 9)*NHEAD + (n >> 6))*SEQ + (m & 511))*DK + (n & 63);
          outh[dst] = h16;
          if (outl) outl[dst] = f2bf(v - bf2f(h16));
        }
  } else {
    // V: transposed [bh][d][s], 4 consecutive s per store
#pragma unroll
    for (int mi = 0; mi < 4; ++mi)
#pragma unroll
      for (int nj = 0; nj < 4; ++nj) {
        int mb = m0 + wr*64 + mi*16 + 4*lg;
        int n = n0 + wc*64 + nj*16 + li;
        int b = mb >> 9, s = mb & 511, d = n & 63;
        unsigned e0 = f2bf(acc[mi][nj][0]);
        unsigned e1 = f2bf(acc[mi][nj][1]);
        unsigned e2 = f2bf(acc[mi][nj][2]);
        unsigned e3 = f2bf(acc[mi][nj][3]);
        uint2 pk; pk.x = e0 | (e1 << 16); pk.y = e2 | (e3 << 16);
        *(uint2*)(outh + ((size_t)(b*NHEAD + head)*DK + d)*SEQ + s) = pk;
      }
  }
}

__global__ void k_sumAB(float* wsf) {
  int i = blockIdx.x * 256 + threadIdx.x;
  if (i < NBH*SEQ) {
    (wsf+WS_AQF)[i] = (0.125f*L2E) * ((wsf+WS_AQM)[i] + (wsf+WS_AQC)[i]);
    (wsf+WS_BKF)[i] = (0.125f*L2E) * ((wsf+WS_BKM)[i] + (wsf+WS_BKC)[i]);
  }
}

// ---------------- fused attention: 2-wave split-j, m1=m2=0 (scores <= 0) ----------------
__global__ __launch_bounds__(128) void k_attn2(float* wsf)
{
  __shared__ float s_bk[SEQ];
  __shared__ float s_tot[2][16];
  __shared__ __align__(16) float s_acc[64][33];

  const unsigned short* qmh = warr(wsf, A_QMH);
  const unsigned short* qml = warr(wsf, A_QML);
  const unsigned short* sch = warr(wsf, A_SCH);
  const unsigned short* scl = warr(wsf, A_SCL);
  const unsigned short* kmh = warr(wsf, A_KMH);
  const unsigned short* skh = warr(wsf, A_SKH);
  const unsigned short* vmT = warr(wsf, A_VMT);
  const unsigned short* vcT = warr(wsf, A_VCT);
  float* omF = wsf + WS_OM;
  float* ocF = wsf + WS_OC;
  const float* AqF = wsf + WS_AQF;
  const float* BkF = wsf + WS_BKF;

  const int tid = threadIdx.x;
  const int l = tid & 63, li = l & 15, lg = l >> 4;
  const int w = tid >> 6;                    // 0..1
  const int blk = blockIdx.x;                // 0..4095
  const int xcd = blk & 7;
  const int q   = blk >> 3;                  // 0..511
  const int bh  = xcd*16 + (q & 15);
  const int rt  = 31 - (q >> 4);             // row-tile 0..31, heavy first
  const int i = rt*16 + li;
  const int ntile = rt + 1;
  const int h0 = (ntile + 1) >> 1;           // wave0: [0,h0), wave1: [h0,ntile)
  const int tstart = w ? h0 : 0;
  const int tend   = w ? ntile : h0;
  const float gam2 = (wsf + WS_GAM)[bh & (NHEAD-1)];   // gamma^2, log2 domain
  const float aq = AqF[(size_t)bh*SEQ + i];

  for (int idx = tid; idx < SEQ; idx += 128) s_bk[idx] = BkF[(size_t)bh*SEQ + idx];

  bf16x8 qf[8];
  {
    const unsigned short* qb[4] = {qmh, qml, sch, scl};
#pragma unroll
    for (int part = 0; part < 2; ++part)
#pragma unroll
      for (int hl = 0; hl < 2; ++hl)
#pragma unroll
        for (int ks = 0; ks < 2; ++ks)
          qf[part*4 + ks*2 + hl] =
            *(const bf16x8*)(qb[part*2+hl] + ((size_t)bh*SEQ + i)*DK + ks*32 + lg*8);
  }
  __syncthreads();

  // scores in log2 domain, always <= 0 (Wasserstein distance is >= 0)
  auto score_tile = [&](int t, float* s) {
    const int j0 = t*16;
    f32x4 accA = {0.f,0.f,0.f,0.f};
    f32x4 accB = {0.f,0.f,0.f,0.f};
    const size_t krow = ((size_t)bh*SEQ + j0 + li)*DK + lg*8;
#pragma unroll
    for (int part = 0; part < 2; ++part) {
      const unsigned short* khp = part ? skh : kmh;
#pragma unroll
      for (int ks = 0; ks < 2; ++ks) {
        bf16x8 kh = *(const bf16x8*)(khp + krow + ks*32);
        accA = MFMA32(kh, qf[part*4+ks*2+0], accA);
        accB = MFMA32(kh, qf[part*4+ks*2+1], accB);
      }
    }
    const float4 bk4 = *(const float4*)&s_bk[j0 + lg*4];
    float bks[4] = {bk4.x, bk4.y, bk4.z, bk4.w};
#pragma unroll
    for (int r = 0; r < 4; ++r) {
      int j = j0 + lg*4 + r;
      float v = (accA[r] + accB[r]) - aq - bks[r];
      s[r] = (j > i) ? -3.0e38f : v;
    }
  };

  // ---- pass 1: per-lane partial tot (m1 = 0), one reduce at end ----
  float totl = 0.f;
  for (int t = tstart; t < tend; ++t) {
    float s[4]; score_tile(t, s);
    totl += exp2f(s[0]) + exp2f(s[1]) + exp2f(s[2]) + exp2f(s[3]);
  }
  totl += __shfl_xor(totl, 16); totl += __shfl_xor(totl, 32);
  if (lg == 0) s_tot[w][li] = totl;
  __syncthreads();
  const float tot = fmaxf(s_tot[0][li] + s_tot[1][li], 1e-35f);
  float run = w ? s_tot[0][li] : 0.f;
  const float g2i = gam2 / tot;

  // ---- pass 2: scan + softmax-2 (m2 = 0) + PV ----
  f32x4 accm[4], accc[4];
  {
    f32x4 z = {0.f,0.f,0.f,0.f};
#pragma unroll
    for (int dt = 0; dt < 4; ++dt) { accm[dt] = z; accc[dt] = z; }
  }
  float sum2l = 0.f;

  auto scan_tile = [&](int t, float* p) {
    float s[4]; score_tile(t, s);
    float e0 = exp2f(s[0]), e1 = exp2f(s[1]), e2 = exp2f(s[2]), e3 = exp2f(s[3]);
    float c0 = e0, c1 = c0+e1, c2 = c1+e2, c3 = c2+e3;
    float a = __shfl_up(c3, 16), b = __shfl_up(c3, 32), c = __shfl_up(c3, 48);
    float excl = (lg >= 1 ? a : 0.f) + (lg >= 2 ? b : 0.f) + (lg >= 3 ? c : 0.f);
    float base = run + excl;
    run = __shfl(base + c3, li + 48);          // new run = old + tile total
    float posb = (float)(i - t*16 - lg*4);
    float cums[4] = {base+c0, base+c1, base+c2, base+c3};
#pragma unroll
    for (int r = 0; r < 4; ++r) {
      float t4 = fmaxf((tot - cums[r]) * (posb - (float)r) * g2i, 0.f);
      float d = sqrtf(t4);
      float eff = fmaxf(exp2f(-d), 1e-5f);
      p[r] = exp2f(s[r] * eff);
      sum2l += p[r];
    }
  };

  for (int t0 = tstart; t0 < tend; t0 += 2) {
    const bool hasB = (t0 + 1) < tend;
    const int j0A = t0*16;
    const int j0B = hasB ? j0A + 16 : j0A;
    // hoist V loads (independent of softmax math)
    union V16 { struct { uint2 lo, hi; } u; bf16x8 v; };
    V16 vm_[4], vc_[4];
#pragma unroll
    for (int dt = 0; dt < 4; ++dt) {
      const size_t vrow = ((size_t)bh*DK + dt*16 + li)*SEQ;
      vm_[dt].u.lo = *(const uint2*)(vmT + vrow + j0A + lg*4);
      vm_[dt].u.hi = *(const uint2*)(vmT + vrow + j0B + lg*4);
      vc_[dt].u.lo = *(const uint2*)(vcT + vrow + j0A + lg*4);
      vc_[dt].u.hi = *(const uint2*)(vcT + vrow + j0B + lg*4);
    }
    float pA[4], pB[4];
    scan_tile(t0, pA);
    if (hasB) scan_tile(t0+1, pB);
    else { pB[0]=pB[1]=pB[2]=pB[3] = 0.f; }
    union PU { uint4 u; bf16x8 v; } pm, pc;
    pm.u.x = pk2bf(pA[0], pA[1]); pm.u.y = pk2bf(pA[2], pA[3]);
    pm.u.z = pk2bf(pB[0], pB[1]); pm.u.w = pk2bf(pB[2], pB[3]);
    pc.u.x = pk2bf(pA[0]*pA[0], pA[1]*pA[1]); pc.u.y = pk2bf(pA[2]*pA[2], pA[3]*pA[3]);
    pc.u.z = pk2bf(pB[0]*pB[0], pB[1]*pB[1]); pc.u.w = pk2bf(pB[2]*pB[2], pB[3]*pB[3]);
#pragma unroll
    for (int dt = 0; dt < 4; ++dt) {
      accm[dt] = MFMA32(vm_[dt].v, pm.v, accm[dt]);
      accc[dt] = MFMA32(vc_[dt].v, pc.v, accc[dt]);
    }
  }

  // ---- merge (no rescale needed: common shift m2 = 0) ----
  sum2l += __shfl_xor(sum2l, 16); sum2l += __shfl_xor(sum2l, 32);
  __syncthreads();
  if (w == 1) {
#pragma unroll
    for (int dt = 0; dt < 4; ++dt)
#pragma unroll
      for (int reg = 0; reg < 4; ++reg) {
        s_acc[l][dt*4 + reg]      = accm[dt][reg];
        s_acc[l][16 + dt*4 + reg] = accc[dt][reg];
      }
    if (lg == 0) s_tot[1][li] = sum2l;
  }
  __syncthreads();
  if (w == 0) {
    const float sum2g = sum2l + s_tot[1][li];
    const float inv2 = 1.0f / sum2g;
    const float inv2c = inv2 * inv2;
    const bool zero = (i == 0);
    float* om_p = omF + ((size_t)bh*SEQ + i)*DK;
    float* oc_p = ocF + ((size_t)bh*SEQ + i)*DK;
#pragma unroll
    for (int dt = 0; dt < 4; ++dt) {
      float4 vm4, vc4;
      vm4.x = (accm[dt][0] + s_acc[l][dt*4+0]) * inv2;
      vm4.y = (accm[dt][1] + s_acc[l][dt*4+1]) * inv2;
      vm4.z = (accm[dt][2] + s_acc[l][dt*4+2]) * inv2;
      vm4.w = (accm[dt][3] + s_acc[l][dt*4+3]) * inv2;
      vc4.x = (accc[dt][0] + s_acc[l][16+dt*4+0]) * inv2c;
      vc4.y = (accc[dt][1] + s_acc[l][16+dt*4+1]) * inv2c;
      vc4.z = (accc[dt][2] + s_acc[l][16+dt*4+2]) * inv2c;
      vc4.w = (accc[dt][3] + s_acc[l][16+dt*4+3]) * inv2c;
      if (zero) { vm4 = make_float4(0.f,0.f,0.f,0.f); vc4 = vm4; }
      *(float4*)(om_p + dt*16 + lg*4) = vm4;
      *(float4*)(oc_p + dt*16 + lg*4) = vc4;
    }
  }
}

// ---------------- output GEMM: 1-term bf16 MFMA ----------------
__global__ __launch_bounds__(256) void k_outM(float* wsf,
                                              const float* w_mean, const float* w_cov,
                                              float* outp)
{
  __shared__ __align__(16) unsigned short Ah[4096];
  __shared__ __align__(16) unsigned short Bh[4096];
  const int y = blockIdx.y;
  const float* A = wsf + (y ? WS_OC : WS_OM);
  const float* W = y ? w_cov : w_mean;
  float* out = outp + (size_t)y * 4194304ull;

  const int tid = threadIdx.x;
  const int l = tid & 63, li = l & 15, lg = l >> 4;
  const int w = tid >> 6, wr = w >> 1, wc = w & 1;
  const int blk = blockIdx.x;
  const int xcd = blk & 7, qq = blk >> 3;
  const int m0 = (xcd*8 + (qq & 7)) * 128;
  const int n0 = (qq >> 3) * 128;
  const int r0 = tid >> 2, c0 = tid & 3, r1 = r0 + 64;
  const int wo0 = r0*64 + ((c0 ^ ((r0>>1)&3))*16);
  const int wo1 = r1*64 + ((c0 ^ ((r1>>1)&3))*16);
  int roA[4], roB[4];
#pragma unroll
  for (int mi = 0; mi < 4; ++mi) {
    int r  = wr*64 + mi*16 + li;
    roA[mi] = r*64 + ((lg ^ ((r>>1)&3))*16);
    int rn = wc*64 + mi*16 + li;
    roB[mi] = rn*64 + ((lg ^ ((rn>>1)&3))*16);
  }
  const int mA0 = m0 + r0, mA1 = m0 + r1;
  const size_t abase0 = ((size_t)(mA0 >> 9) * NHEAD * SEQ + (mA0 & 511)) * DK;
  const size_t abase1 = ((size_t)(mA1 >> 9) * NHEAD * SEQ + (mA1 & 511)) * DK;
  const float* wp0 = W + (size_t)(n0 + r0)*DMODEL + c0*8;
  const float* wp1 = W + (size_t)(n0 + r1)*DMODEL + c0*8;

  auto acvt = [&](size_t abase, int k) -> uint4 {
    const float* p = A + abase + (size_t)(k >> 6) * (SEQ*DK) + (k & 63);
    return cvt8h(p);
  };

  int k0 = c0*8;
  uint4 a0 = acvt(abase0, k0);
  uint4 a1 = acvt(abase1, k0);
  uint4 b0 = cvt8h(wp0);
  uint4 b1 = cvt8h(wp1);

  f32x4 acc[4][4];
  f32x4 z = {0.f,0.f,0.f,0.f};
#pragma unroll
  for (int a = 0; a < 4; ++a)
#pragma unroll
    for (int b = 0; b < 4; ++b) acc[a][b] = z;

  for (int kt = 0; kt < DMODEL; kt += 32) {
    __syncthreads();
    *(uint4*)((char*)Ah + wo0) = a0;
    *(uint4*)((char*)Ah + wo1) = a1;
    *(uint4*)((char*)Bh + wo0) = b0;
    *(uint4*)((char*)Bh + wo1) = b1;
    __syncthreads();
    if (kt + 32 < DMODEL) {
      int kn = kt + 32 + c0*8;
      a0 = acvt(abase0, kn);
      a1 = acvt(abase1, kn);
      b0 = cvt8h(wp0 + kt + 32);
      b1 = cvt8h(wp1 + kt + 32);
    }
    bf16x8 ah[4], bh[4];
#pragma unroll
    for (int mi = 0; mi < 4; ++mi) {
      ah[mi] = *(const bf16x8*)((const char*)Ah + roA[mi]);
      bh[mi] = *(const bf16x8*)((const char*)Bh + roB[mi]);
    }
#pragma unroll
    for (int mi = 0; mi < 4; ++mi)
#pragma unroll
      for (int nj = 0; nj < 4; ++nj)
        acc[mi][nj] = MFMA32(ah[mi], bh[nj], acc[mi][nj]);
  }
#pragma unroll
  for (int mi = 0; mi < 4; ++mi)
#pragma unroll
    for (int nj = 0; nj < 4; ++nj)
#pragma unroll
      for (int reg = 0; reg < 4; ++reg) {
        int m = m0 + wr*64 + mi*16 + 4*lg + reg;
        int n = n0 + wc*64 + nj*16 + li;
        out[(size_t)m*DMODEL + n] = acc[mi][nj][reg];
      }
}

extern "C" void kernel_launch(void* const* d_in, const int* in_sizes, int n_in,
                              void* d_out, int out_size, void* d_ws, size_t ws_size,
                              hipStream_t stream) {
  (void)in_sizes; (void)n_in; (void)out_size; (void)ws_size;
  float* wsf = (float*)d_ws;

  k_gamma<<<1, 64, 0, stream>>>((const float*)d_in[14], wsf);
  k_projM<<<dim3(256, 6), 256, 0, stream>>>(
      (const float*)d_in[0], (const float*)d_in[1],
      (const float*)d_in[2], (const float*)d_in[3],
      (const float*)d_in[4], (const float*)d_in[5],
      (const float*)d_in[6], (const float*)d_in[7],
      (const float*)d_in[8], (const float*)d_in[9],
      (const float*)d_in[10], (const float*)d_in[11],
      wsf);
  k_sumAB<<<256, 256, 0, stream>>>(wsf);
  k_attn2<<<4096, 128, 0, stream>>>(wsf);
  k_outM<<<dim3(256, 2), 256, 0, stream>>>(wsf, (const float*)d_in[12],
                                           (const float*)d_in[13], (float*)d_out);
}

// Round 13
// 217.317 us; speedup vs baseline: 1.2341x; 1.1091x over previous
//
#include <hip/hip_runtime.h>
#include <hip/hip_bf16.h>

#define SEQ    512
#define DMODEL 512
#define NHEAD  8
#define DK     64
#define BS     16
#define NBH    (BS*NHEAD)       // 128
#define HSZ    (SEQ*DK)         // 32768 per (b,h)
#define L2E    1.4426950408889634f

typedef __attribute__((ext_vector_type(8))) short bf16x8;
typedef __attribute__((ext_vector_type(4))) float f32x4;

#define MFMA32(A,B,C) __builtin_amdgcn_mfma_f32_16x16x32_bf16(A,B,C,0,0,0)

// ---------------- workspace layout (fp32 units) ----------------
#define WS_GAM 16ull
#define WS_AQM 256ull
#define WS_AQC (WS_AQM +  65536ull)
#define WS_BKM (WS_AQM + 131072ull)
#define WS_BKC (WS_AQM + 196608ull)
#define WS_AQF (WS_AQM + 262144ull)
#define WS_BKF (WS_AQM + 327680ull)
#define WS_OM  1048576ull
#define WS_OC  (WS_OM + 4194304ull)
#define WS_BF  (WS_OC + 4194304ull)     // bf16 arrays region
#define ARRE   4194304ull               // elems per bf16 array
// bf16 array ids
#define A_QMH 0
#define A_QML 1
#define A_SCH 2
#define A_SCL 3
#define A_KMH 4
#define A_SKH 6
#define A_VMT 8
#define A_VCT 9

__device__ __forceinline__ unsigned short* warr(float* wsf, int idx) {
  return (unsigned short*)(wsf + WS_BF) + (size_t)idx * ARRE;
}

// ---------- helpers ----------
__device__ __forceinline__ float bf2f(unsigned short h) {
  union { float f; unsigned u; } v; v.u = ((unsigned)h) << 16; return v.f;
}
__device__ __forceinline__ unsigned short f2bf(float f) {
  union { float f; unsigned u; } v; v.f = f;
  unsigned u = v.u;
  u += 0x7FFFu + ((u >> 16) & 1u);   // RNE
  return (unsigned short)(u >> 16);
}
__device__ __forceinline__ void ld8_f32(const float* p, float* v) {
  float4 a = *(const float4*)p; float4 b = *(const float4*)(p+4);
  v[0]=a.x;v[1]=a.y;v[2]=a.z;v[3]=a.w;v[4]=b.x;v[5]=b.y;v[6]=b.z;v[7]=b.w;
}
// pack 2 fp32 -> [bf16(a) | bf16(b)<<16], round-half-up, via v_perm
__device__ __forceinline__ unsigned pk2bf(float a, float b) {
  union { float f; unsigned u; } x, y;
  x.f = a; y.f = b;
  return __builtin_amdgcn_perm(y.u + 0x8000u, x.u + 0x8000u, 0x07060302u);
}
__device__ __forceinline__ uint4 cvt8r(const float* t8) {
  uint4 h;
  h.x = pk2bf(t8[0], t8[1]);
  h.y = pk2bf(t8[2], t8[3]);
  h.z = pk2bf(t8[4], t8[5]);
  h.w = pk2bf(t8[6], t8[7]);
  return h;
}
__device__ __forceinline__ uint4 cvt8h(const float* p) {
  float t8[8]; ld8_f32(p, t8); return cvt8r(t8);
}

__global__ void k_gamma(const float* __restrict__ g_in, float* __restrict__ wsf) {
  int t = threadIdx.x;
  if (t >= NHEAD) return;
  float g = g_in[t];
  float sp = (g > 20.f) ? g : log1pf(expf(g));
  float gl = sp * L2E;                 // |gamma| in log2 domain
  (wsf + WS_GAM)[t] = gl * gl;         // store gamma^2 (log2 domain)
}

// ---------------- projections: 1-term bf16 MFMA (consistent rounding) ----------------
// y: 0 qm, 1 km, 2 qc, 3 kc, 4 vm, 5 vc
__global__ __launch_bounds__(256) void k_projM(
    const float* xqm, const float* xqc, const float* xkm, const float* xkc,
    const float* xvm, const float* xvc,
    const float* wqm, const float* wqc, const float* wkm, const float* wkc,
    const float* wvm, const float* wvc,
    float* wsf)
{
  __shared__ __align__(16) unsigned short Ah[4096];
  __shared__ __align__(16) unsigned short Bh[4096];
  const int y = blockIdx.y;
  const float* X; const float* W;
  unsigned short *outh = nullptr, *outl = nullptr;
  float* sums = nullptr;
  float qscale = 1.0f; int mode = 0;  // 0 mean, 1 cov, 2 v
  switch (y) {
    case 0: X=xqm; W=wqm; outh=warr(wsf,A_QMH); outl=warr(wsf,A_QML); sums=wsf+WS_AQM; qscale=0.25f*L2E; mode=0; break;
    case 1: X=xkm; W=wkm; outh=warr(wsf,A_KMH); outl=nullptr;         sums=wsf+WS_BKM; qscale=1.0f;      mode=0; break;
    case 2: X=xqc; W=wqc; outh=warr(wsf,A_SCH); outl=warr(wsf,A_SCL); sums=wsf+WS_AQC; qscale=0.25f*L2E; mode=1; break;
    case 3: X=xkc; W=wkc; outh=warr(wsf,A_SKH); outl=nullptr;         sums=wsf+WS_BKC; qscale=1.0f;      mode=1; break;
    case 4: X=xvm; W=wvm; outh=warr(wsf,A_VMT); mode=2; break;
    default:X=xvc; W=wvc; outh=warr(wsf,A_VCT); mode=2; break;
  }
  const int tid = threadIdx.x;
  const int l = tid & 63, li = l & 15, lg = l >> 4;
  const int w = tid >> 6, wr = w >> 1, wc = w & 1;
  const int blk = blockIdx.x;
  const int xcd = blk & 7, qq = blk >> 3;           // qq 0..31
  const int m0 = (xcd*8 + (qq & 7)) * 128;
  const int n0 = (qq >> 3) * 128;
  const int r0 = tid >> 2, c0 = tid & 3, r1 = r0 + 64;
  const int wo0 = r0*64 + ((c0 ^ ((r0>>1)&3))*16);
  const int wo1 = r1*64 + ((c0 ^ ((r1>>1)&3))*16);
  int roA[4], roB[4];
#pragma unroll
  for (int mi = 0; mi < 4; ++mi) {
    int r  = wr*64 + mi*16 + li;
    roA[mi] = r*64 + ((lg ^ ((r>>1)&3))*16);
    int rn = wc*64 + mi*16 + li;
    roB[mi] = rn*64 + ((lg ^ ((rn>>1)&3))*16);
  }
  const float* xp0 = X + (size_t)(m0+r0)*DMODEL + c0*8;
  const float* xp1 = X + (size_t)(m0+r1)*DMODEL + c0*8;
  const float* wp0 = W + (size_t)(n0+r0)*DMODEL + c0*8;
  const float* wp1 = W + (size_t)(n0+r1)*DMODEL + c0*8;
  uint4 a0 = cvt8h(xp0);
  uint4 a1 = cvt8h(xp1);
  uint4 b0 = cvt8h(wp0);
  uint4 b1 = cvt8h(wp1);

  f32x4 acc[4][4];
  f32x4 z = {0.f,0.f,0.f,0.f};
#pragma unroll
  for (int a = 0; a < 4; ++a)
#pragma unroll
    for (int b = 0; b < 4; ++b) acc[a][b] = z;

  for (int kt = 0; kt < DMODEL; kt += 32) {
    __syncthreads();
    *(uint4*)((char*)Ah + wo0) = a0;
    *(uint4*)((char*)Ah + wo1) = a1;
    *(uint4*)((char*)Bh + wo0) = b0;
    *(uint4*)((char*)Bh + wo1) = b1;
    __syncthreads();
    if (kt + 32 < DMODEL) {
      a0 = cvt8h(xp0 + kt + 32);
      a1 = cvt8h(xp1 + kt + 32);
      b0 = cvt8h(wp0 + kt + 32);
      b1 = cvt8h(wp1 + kt + 32);
    }
    bf16x8 ah[4], bh[4];
#pragma unroll
    for (int mi = 0; mi < 4; ++mi) {
      ah[mi] = *(const bf16x8*)((const char*)Ah + roA[mi]);
      bh[mi] = *(const bf16x8*)((const char*)Bh + roB[mi]);
    }
#pragma unroll
    for (int mi = 0; mi < 4; ++mi)
#pragma unroll
      for (int nj = 0; nj < 4; ++nj)
        acc[mi][nj] = MFMA32(ah[mi], bh[nj], acc[mi][nj]);
  }

  const int head = ((n0 >> 6) + wc);
  if (mode <= 1) {
    const bool kside = (outl == nullptr);
#pragma unroll
    for (int mi = 0; mi < 4; ++mi)
#pragma unroll
      for (int reg = 0; reg < 4; ++reg) {
        float rs = 0.f;
#pragma unroll
        for (int nj = 0; nj < 4; ++nj) {
          float v = acc[mi][nj][reg];
          if (mode == 0) {
            float vs = (kside) ? bf2f(f2bf(v)) : v;   // consistent with stored K
            rs += vs*vs;
          } else {
            rs += v;                                   // raw cov sum (reference semantics)
          }
        }
        rs += __shfl_xor(rs, 1); rs += __shfl_xor(rs, 2);
        rs += __shfl_xor(rs, 4); rs += __shfl_xor(rs, 8);
        if (li == 0) {
          int m = m0 + wr*64 + mi*16 + 4*lg + reg;
          sums[((size_t)(m >> 9)*NHEAD + head)*SEQ + (m & 511)] = rs;
        }
      }
#pragma unroll
    for (int mi = 0; mi < 4; ++mi)
#pragma unroll
      for (int nj = 0; nj < 4; ++nj)
#pragma unroll
        for (int reg = 0; reg < 4; ++reg) {
          float v = acc[mi][nj][reg];
          if (mode == 1) v = sqrtf(fmaxf(v, 1e-24f));
          v *= qscale;
          unsigned short h16 = f2bf(v);
          int m = m0 + wr*64 + mi*16 + 4*lg + reg;
          int n = n0 + wc*64 + nj*16 + li;
          size_t dst = ((size_t)((m >> 9)*NHEAD + (n >> 6))*SEQ + (m & 511))*DK + (n & 63);
          outh[dst] = h16;
          if (outl) outl[dst] = f2bf(v - bf2f(h16));
        }
  } else {
    // V: transposed [bh][d][s], 4 consecutive s per store
#pragma unroll
    for (int mi = 0; mi < 4; ++mi)
#pragma unroll
      for (int nj = 0; nj < 4; ++nj) {
        int mb = m0 + wr*64 + mi*16 + 4*lg;
        int n = n0 + wc*64 + nj*16 + li;
        int b = mb >> 9, s = mb & 511, d = n & 63;
        unsigned e0 = f2bf(acc[mi][nj][0]);
        unsigned e1 = f2bf(acc[mi][nj][1]);
        unsigned e2 = f2bf(acc[mi][nj][2]);
        unsigned e3 = f2bf(acc[mi][nj][3]);
        uint2 pk; pk.x = e0 | (e1 << 16); pk.y = e2 | (e3 << 16);
        *(uint2*)(outh + ((size_t)(b*NHEAD + head)*DK + d)*SEQ + s) = pk;
      }
  }
}

__global__ void k_sumAB(float* wsf) {
  int i = blockIdx.x * 256 + threadIdx.x;
  if (i < NBH*SEQ) {
    (wsf+WS_AQF)[i] = (0.125f*L2E) * ((wsf+WS_AQM)[i] + (wsf+WS_AQC)[i]);
    (wsf+WS_BKF)[i] = (0.125f*L2E) * ((wsf+WS_BKM)[i] + (wsf+WS_BKC)[i]);
  }
}

// ---------------- fused attention: score-stash in LDS, K prefetch, uniform blocks ----
// block = (bh, pp); processes row-tiles {31-pp, pp} sequentially (33 j-tiles total).
// 2 waves split the j-range of the current row-tile; scores computed ONCE (pass A),
// stashed in swizzled LDS, re-read in pass B (scan + softmax-2 + PV).
__global__ __launch_bounds__(128) void k_attn2(float* wsf)
{
  __shared__ __align__(16) float s_s[16*544];   // 34816 B; aliased as s_acc[64][33] in merge
  __shared__ float s_bk[SEQ];
  __shared__ float s_tot[2][16];
  float (*s_acc)[33] = (float(*)[33])s_s;

  const unsigned short* qmh = warr(wsf, A_QMH);
  const unsigned short* qml = warr(wsf, A_QML);
  const unsigned short* sch = warr(wsf, A_SCH);
  const unsigned short* scl = warr(wsf, A_SCL);
  const unsigned short* kmh = warr(wsf, A_KMH);
  const unsigned short* skh = warr(wsf, A_SKH);
  const unsigned short* vmT = warr(wsf, A_VMT);
  const unsigned short* vcT = warr(wsf, A_VCT);
  float* omF = wsf + WS_OM;
  float* ocF = wsf + WS_OC;
  const float* AqF = wsf + WS_AQF;
  const float* BkF = wsf + WS_BKF;

  const int tid = threadIdx.x;
  const int l = tid & 63, li = l & 15, lg = l >> 4;
  const int w = tid >> 6;                    // 0..1
  const int blk = blockIdx.x;                // 0..2047
  const int xcd = blk & 7;
  const int q   = blk >> 3;                  // 0..255
  const int bh  = xcd*16 + (q & 15);
  const int pp  = q >> 4;                    // 0..15
  const float gam2 = (wsf + WS_GAM)[bh & (NHEAD-1)];   // gamma^2, log2 domain

  for (int idx = tid; idx < SEQ; idx += 128) s_bk[idx] = BkF[(size_t)bh*SEQ + idx];

  // swizzled LDS index for this lane's float4 slot of tile t (stride 544, %32==0)
  auto sidx = [&](int t) -> int {
    int c = t*16 + lg*4;
    return li*544 + (c ^ ((li & 7) << 2));
  };

  for (int ph = 0; ph < 2; ++ph) {
    const int rt = ph ? pp : (31 - pp);      // heavy first
    const int i = rt*16 + li;
    const int ntile = rt + 1;
    const int h0 = (ntile + 1) >> 1;         // wave0: [0,h0), wave1: [h0,ntile)
    const int tstart = w ? h0 : 0;
    const int tend   = w ? ntile : h0;
    const float aq = AqF[(size_t)bh*SEQ + i];

    __syncthreads();   // s_bk ready (ph0); s_s/s_tot reuse safe (ph1)

    // Q fragments: [part*4 + ks*2 + hl]
    bf16x8 qf[8];
    {
      const unsigned short* qb[4] = {qmh, qml, sch, scl};
#pragma unroll
      for (int part = 0; part < 2; ++part)
#pragma unroll
        for (int hl = 0; hl < 2; ++hl)
#pragma unroll
          for (int ks = 0; ks < 2; ++ks)
            qf[part*4 + ks*2 + hl] =
              *(const bf16x8*)(qb[part*2+hl] + ((size_t)bh*SEQ + i)*DK + ks*32 + lg*8);
    }

    auto kload = [&](int t, bf16x8* kr) {
      const size_t kr0 = ((size_t)bh*SEQ + t*16 + li)*DK + lg*8;
      kr[0] = *(const bf16x8*)(kmh + kr0);
      kr[1] = *(const bf16x8*)(kmh + kr0 + 32);
      kr[2] = *(const bf16x8*)(skh + kr0);
      kr[3] = *(const bf16x8*)(skh + kr0 + 32);
    };

    // ---- pass A: score once -> LDS stash + local tot (m1 = 0; scores <= 0) ----
    float totl = 0.f;
    {
      bf16x8 kc[4], kn[4];
      if (tstart < tend) kload(tstart, kc);
      for (int t = tstart; t < tend; ++t) {
        const bool more = (t + 1) < tend;
        if (more) kload(t + 1, kn);
        f32x4 accA = {0.f,0.f,0.f,0.f};
        f32x4 accB = {0.f,0.f,0.f,0.f};
        accA = MFMA32(kc[0], qf[0], accA); accB = MFMA32(kc[0], qf[1], accB);
        accA = MFMA32(kc[1], qf[2], accA); accB = MFMA32(kc[1], qf[3], accB);
        accA = MFMA32(kc[2], qf[4], accA); accB = MFMA32(kc[2], qf[5], accB);
        accA = MFMA32(kc[3], qf[6], accA); accB = MFMA32(kc[3], qf[7], accB);
        const float4 bk4 = *(const float4*)&s_bk[t*16 + lg*4];
        float s0 = (accA[0]+accB[0]) - aq - bk4.x;
        float s1 = (accA[1]+accB[1]) - aq - bk4.y;
        float s2 = (accA[2]+accB[2]) - aq - bk4.z;
        float s3 = (accA[3]+accB[3]) - aq - bk4.w;
        const int jb = t*16 + lg*4;
        if (jb + 0 > i) s0 = -3.0e38f;
        if (jb + 1 > i) s1 = -3.0e38f;
        if (jb + 2 > i) s2 = -3.0e38f;
        if (jb + 3 > i) s3 = -3.0e38f;
        totl += exp2f(s0) + exp2f(s1) + exp2f(s2) + exp2f(s3);
        *(float4*)&s_s[sidx(t)] = make_float4(s0, s1, s2, s3);
        if (more) {
#pragma unroll
          for (int x = 0; x < 4; ++x) kc[x] = kn[x];
        }
      }
    }
    totl += __shfl_xor(totl, 16); totl += __shfl_xor(totl, 32);
    if (lg == 0) s_tot[w][li] = totl;
    __syncthreads();
    const float tot = fmaxf(s_tot[0][li] + s_tot[1][li], 1e-35f);
    float run = w ? s_tot[0][li] : 0.f;
    const float g2i = gam2 / tot;

    // ---- pass B: LDS-sourced scan + softmax-2 (m2 = 0) + PV ----
    f32x4 accm[4], accc[4];
    {
      f32x4 z = {0.f,0.f,0.f,0.f};
#pragma unroll
      for (int dt = 0; dt < 4; ++dt) { accm[dt] = z; accc[dt] = z; }
    }
    float sum2l = 0.f;

    auto scan_tile = [&](int t, float* p) {
      const float4 sv = *(const float4*)&s_s[sidx(t)];
      const float e0 = exp2f(sv.x), e1 = exp2f(sv.y),
                  e2 = exp2f(sv.z), e3 = exp2f(sv.w);
      float c0 = e0, c1 = c0+e1, c2 = c1+e2, c3 = c2+e3;
      float a = __shfl_up(c3, 16), b = __shfl_up(c3, 32), c = __shfl_up(c3, 48);
      float excl = (lg >= 1 ? a : 0.f) + (lg >= 2 ? b : 0.f) + (lg >= 3 ? c : 0.f);
      float base = run + excl;
      run = __shfl(base + c3, li + 48);        // new run = old + tile total
      float posb = (float)(i - t*16 - lg*4);
      float cums[4] = {base+c0, base+c1, base+c2, base+c3};
      float ss[4] = {sv.x, sv.y, sv.z, sv.w};
#pragma unroll
      for (int r = 0; r < 4; ++r) {
        float t4 = fmaxf((tot - cums[r]) * (posb - (float)r) * g2i, 0.f);
        float d = sqrtf(t4);
        float eff = fmaxf(exp2f(-d), 1e-5f);
        p[r] = exp2f(ss[r] * eff);
        sum2l += p[r];
      }
    };

    for (int t0 = tstart; t0 < tend; t0 += 2) {
      const bool hasB = (t0 + 1) < tend;
      const int j0A = t0*16;
      const int j0B = hasB ? j0A + 16 : j0A;
      // hoist V loads (independent of softmax math)
      union V16 { struct { uint2 lo, hi; } u; bf16x8 v; };
      V16 vm_[4], vc_[4];
#pragma unroll
      for (int dt = 0; dt < 4; ++dt) {
        const size_t vrow = ((size_t)bh*DK + dt*16 + li)*SEQ;
        vm_[dt].u.lo = *(const uint2*)(vmT + vrow + j0A + lg*4);
        vm_[dt].u.hi = *(const uint2*)(vmT + vrow + j0B + lg*4);
        vc_[dt].u.lo = *(const uint2*)(vcT + vrow + j0A + lg*4);
        vc_[dt].u.hi = *(const uint2*)(vcT + vrow + j0B + lg*4);
      }
      float pA[4], pB[4];
      scan_tile(t0, pA);
      if (hasB) scan_tile(t0+1, pB);
      else { pB[0]=pB[1]=pB[2]=pB[3] = 0.f; }
      union PU { uint4 u; bf16x8 v; } pm, pc;
      pm.u.x = pk2bf(pA[0], pA[1]); pm.u.y = pk2bf(pA[2], pA[3]);
      pm.u.z = pk2bf(pB[0], pB[1]); pm.u.w = pk2bf(pB[2], pB[3]);
      pc.u.x = pk2bf(pA[0]*pA[0], pA[1]*pA[1]); pc.u.y = pk2bf(pA[2]*pA[2], pA[3]*pA[3]);
      pc.u.z = pk2bf(pB[0]*pB[0], pB[1]*pB[1]); pc.u.w = pk2bf(pB[2]*pB[2], pB[3]*pB[3]);
#pragma unroll
      for (int dt = 0; dt < 4; ++dt) {
        accm[dt] = MFMA32(vm_[dt].v, pm.v, accm[dt]);
        accc[dt] = MFMA32(vc_[dt].v, pc.v, accc[dt]);
      }
    }

    // ---- merge (no rescale: common shift m2 = 0); s_acc aliases s_s ----
    sum2l += __shfl_xor(sum2l, 16); sum2l += __shfl_xor(sum2l, 32);
    __syncthreads();   // all s_s reads done before alias writes
    if (w == 1) {
#pragma unroll
      for (int dt = 0; dt < 4; ++dt)
#pragma unroll
        for (int reg = 0; reg < 4; ++reg) {
          s_acc[l][dt*4 + reg]      = accm[dt][reg];
          s_acc[l][16 + dt*4 + reg] = accc[dt][reg];
        }
      if (lg == 0) s_tot[1][li] = sum2l;
    }
    __syncthreads();
    if (w == 0) {
      const float sum2g = sum2l + s_tot[1][li];
      const float inv2 = 1.0f / sum2g;
      const float inv2c = inv2 * inv2;
      const bool zero = (i == 0);
      float* om_p = omF + ((size_t)bh*SEQ + i)*DK;
      float* oc_p = ocF + ((size_t)bh*SEQ + i)*DK;
#pragma unroll
      for (int dt = 0; dt < 4; ++dt) {
        float4 vm4, vc4;
        vm4.x = (accm[dt][0] + s_acc[l][dt*4+0]) * inv2;
        vm4.y = (accm[dt][1] + s_acc[l][dt*4+1]) * inv2;
        vm4.z = (accm[dt][2] + s_acc[l][dt*4+2]) * inv2;
        vm4.w = (accm[dt][3] + s_acc[l][dt*4+3]) * inv2;
        vc4.x = (accc[dt][0] + s_acc[l][16+dt*4+0]) * inv2c;
        vc4.y = (accc[dt][1] + s_acc[l][16+dt*4+1]) * inv2c;
        vc4.z = (accc[dt][2] + s_acc[l][16+dt*4+2]) * inv2c;
        vc4.w = (accc[dt][3] + s_acc[l][16+dt*4+3]) * inv2c;
        if (zero) { vm4 = make_float4(0.f,0.f,0.f,0.f); vc4 = vm4; }
        *(float4*)(om_p + dt*16 + lg*4) = vm4;
        *(float4*)(oc_p + dt*16 + lg*4) = vc4;
      }
    }
  }
}

// ---------------- output GEMM: 1-term bf16 MFMA ----------------
__global__ __launch_bounds__(256) void k_outM(float* wsf,
                                              const float* w_mean, const float* w_cov,
                                              float* outp)
{
  __shared__ __align__(16) unsigned short Ah[4096];
  __shared__ __align__(16) unsigned short Bh[4096];
  const int y = blockIdx.y;
  const float* A = wsf + (y ? WS_OC : WS_OM);
  const float* W = y ? w_cov : w_mean;
  float* out = outp + (size_t)y * 4194304ull;

  const int tid = threadIdx.x;
  const int l = tid & 63, li = l & 15, lg = l >> 4;
  const int w = tid >> 6, wr = w >> 1, wc = w & 1;
  const int blk = blockIdx.x;
  const int xcd = blk & 7, qq = blk >> 3;
  const int m0 = (xcd*8 + (qq & 7)) * 128;
  const int n0 = (qq >> 3) * 128;
  const int r0 = tid >> 2, c0 = tid & 3, r1 = r0 + 64;
  const int wo0 = r0*64 + ((c0 ^ ((r0>>1)&3))*16);
  const int wo1 = r1*64 + ((c0 ^ ((r1>>1)&3))*16);
  int roA[4], roB[4];
#pragma unroll
  for (int mi = 0; mi < 4; ++mi) {
    int r  = wr*64 + mi*16 + li;
    roA[mi] = r*64 + ((lg ^ ((r>>1)&3))*16);
    int rn = wc*64 + mi*16 + li;
    roB[mi] = rn*64 + ((lg ^ ((rn>>1)&3))*16);
  }
  const int mA0 = m0 + r0, mA1 = m0 + r1;
  const size_t abase0 = ((size_t)(mA0 >> 9) * NHEAD * SEQ + (mA0 & 511)) * DK;
  const size_t abase1 = ((size_t)(mA1 >> 9) * NHEAD * SEQ + (mA1 & 511)) * DK;
  const float* wp0 = W + (size_t)(n0 + r0)*DMODEL + c0*8;
  const float* wp1 = W + (size_t)(n0 + r1)*DMODEL + c0*8;

  auto acvt = [&](size_t abase, int k) -> uint4 {
    const float* p = A + abase + (size_t)(k >> 6) * (SEQ*DK) + (k & 63);
    return cvt8h(p);
  };

  int k0 = c0*8;
  uint4 a0 = acvt(abase0, k0);
  uint4 a1 = acvt(abase1, k0);
  uint4 b0 = cvt8h(wp0);
  uint4 b1 = cvt8h(wp1);

  f32x4 acc[4][4];
  f32x4 z = {0.f,0.f,0.f,0.f};
#pragma unroll
  for (int a = 0; a < 4; ++a)
#pragma unroll
    for (int b = 0; b < 4; ++b) acc[a][b] = z;

  for (int kt = 0; kt < DMODEL; kt += 32) {
    __syncthreads();
    *(uint4*)((char*)Ah + wo0) = a0;
    *(uint4*)((char*)Ah + wo1) = a1;
    *(uint4*)((char*)Bh + wo0) = b0;
    *(uint4*)((char*)Bh + wo1) = b1;
    __syncthreads();
    if (kt + 32 < DMODEL) {
      int kn = kt + 32 + c0*8;
      a0 = acvt(abase0, kn);
      a1 = acvt(abase1, kn);
      b0 = cvt8h(wp0 + kt + 32);
      b1 = cvt8h(wp1 + kt + 32);
    }
    bf16x8 ah[4], bh[4];
#pragma unroll
    for (int mi = 0; mi < 4; ++mi) {
      ah[mi] = *(const bf16x8*)((const char*)Ah + roA[mi]);
      bh[mi] = *(const bf16x8*)((const char*)Bh + roB[mi]);
    }
#pragma unroll
    for (int mi = 0; mi < 4; ++mi)
#pragma unroll
      for (int nj = 0; nj < 4; ++nj)
        acc[mi][nj] = MFMA32(ah[mi], bh[nj], acc[mi][nj]);
  }
#pragma unroll
  for (int mi = 0; mi < 4; ++mi)
#pragma unroll
    for (int nj = 0; nj < 4; ++nj)
#pragma unroll
      for (int reg = 0; reg < 4; ++reg) {
        int m = m0 + wr*64 + mi*16 + 4*lg + reg;
        int n = n0 + wc*64 + nj*16 + li;
        out[(size_t)m*DMODEL + n] = acc[mi][nj][reg];
      }
}

extern "C" void kernel_launch(void* const* d_in, const int* in_sizes, int n_in,
                              void* d_out, int out_size, void* d_ws, size_t ws_size,
                              hipStream_t stream) {
  (void)in_sizes; (void)n_in; (void)out_size; (void)ws_size;
  float* wsf = (float*)d_ws;

  k_gamma<<<1, 64, 0, stream>>>((const float*)d_in[14], wsf);
  k_projM<<<dim3(256, 6), 256, 0, stream>>>(
      (const float*)d_in[0], (const float*)d_in[1],
      (const float*)d_in[2], (const float*)d_in[3],
      (const float*)d_in[4], (const float*)d_in[5],
      (const float*)d_in[6], (const float*)d_in[7],
      (const float*)d_in[8], (const float*)d_in[9],
      (const float*)d_in[10], (const float*)d_in[11],
      wsf);
  k_sumAB<<<256, 256, 0, stream>>>(wsf);
  k_attn2<<<2048, 128, 0, stream>>>(wsf);
  k_outM<<<dim3(256, 2), 256, 0, stream>>>(wsf, (const float*)d_in[12],
                                           (const float*)d_in[13], (float*)d_out);
}